// Round 14
// baseline (1864.063 us; speedup 1.0000x reference)
//
#include <hip/hip_runtime.h>
#include <cmath>

#define EPS 1e-5f

typedef _Float16 half_t;
typedef __attribute__((ext_vector_type(8))) _Float16 half8;
typedef __attribute__((ext_vector_type(8))) short short8;
typedef __attribute__((ext_vector_type(4))) float f32x4;
typedef __attribute__((ext_vector_type(2))) unsigned int uint2v;

__device__ __forceinline__ int reflect_idx(int p, int S) {
    if (p < 0) p = -p;
    if (p >= S) p = 2 * S - 2 - p;
    return p;
}
__device__ __forceinline__ float hlo(unsigned v) {
    return (float)__builtin_bit_cast(half_t, (unsigned short)(v & 0xffffu));
}
__device__ __forceinline__ float hhi(unsigned v) {
    return (float)__builtin_bit_cast(half_t, (unsigned short)(v >> 16));
}
__device__ __forceinline__ unsigned short hbits(float f) {
    return __builtin_bit_cast(unsigned short, (half_t)f);
}

// async global->LDS DMA, 16B per lane; lds dest = wave-uniform base + lane*16
__device__ __forceinline__ void gl_lds16(const half_t* g, char* l) {
    __builtin_amdgcn_global_load_lds(
        (const __attribute__((address_space(1))) unsigned int*)g,
        (__attribute__((address_space(3))) unsigned int*)l, 16, 0, 0);
}

// ---------------- weight transforms (fp32 -> fp16) ----------------
// conv weights [Co][Cin][KK] -> [cb][kk][Cop][32] where c = cb*32 + cl.
__global__ void wtrans_conv(const float* __restrict__ w, half_t* __restrict__ wt,
                            int Co, int Cop, int Cin, int KK)
{
    int i = blockIdx.x * 256 + threadIdx.x;
    int total = KK * Cop * Cin;
    if (i >= total) return;
    int cl = i & 31;
    int oc = (i >> 5) % Cop;
    int rest = (i >> 5) / Cop;     // cb*KK + kk
    int kk = rest % KK;
    int cb = rest / KK;
    int c = (cb << 5) + cl;
    float v = (oc < Co) ? w[((size_t)oc * Cin + c) * KK + kk] : 0.f;
    wt[i] = (half_t)v;
}

// dcn weights [Co][Cin][9] -> [cb][Co][32] with kidx = k*Cin + c = cb*32 + cl
__global__ void wtrans_dcn(const float* __restrict__ w, half_t* __restrict__ wt,
                           int Co, int Cin)
{
    int i = blockIdx.x * 256 + threadIdx.x;
    int total = Co * 9 * Cin;
    if (i >= total) return;
    int cl = i & 31;
    int oc = (i >> 5) % Co;
    int cb = (i >> 5) / Co;
    int kidx = (cb << 5) + cl;
    int k = kidx / Cin, c = kidx % Cin;
    wt[i] = (half_t)w[((size_t)oc * Cin + c) * 9 + k];
}

// ---------------- NCHW fp32 -> NHWC fp16 (+ optional fp32 NHWC copy) ----------------
__global__ void cvt_nchw_nhwc(const float* __restrict__ in, half_t* __restrict__ out,
                              float* __restrict__ outf, int C, int H, int W, int total)
{
    int i = blockIdx.x * 256 + threadIdx.x;
    if (i >= total) return;
    int c = i % C;
    int x = (i / C) % W;
    int y = (i / (C * W)) % H;
    int b = i / (C * W * H);
    float v = in[(((size_t)b * C + c) * H + y) * W + x];
    out[i] = (half_t)v;
    if (outf) outf[i] = v;
}

// ---------------- MFMA implicit-GEMM conv ----------------
// TH=8 x TW positions x COB ocs per block, 4 waves arranged WM x (4/WM).
// WM=1: all waves share m-range (A dedups via L1), NM=COB/16 maximizes
// B-fragment reuse (LDS reads/MFMA = 1/NM). DMA staging, double-buffered.
// outfmt: 0 = fp16 NHWC (stride Co), 1 = fp32 NCHW (guarded), 2 = fp32 NHWC.
template<int K, int UP, int REFLECT, int COB, int WM, int TW, int MINW>
__global__ __launch_bounds__(256, MINW)
void mfma_conv(const half_t* __restrict__ in1, const half_t* __restrict__ in2,
               int C1, int C2,
               const half_t* __restrict__ wt, const float* __restrict__ bias,
               void* __restrict__ outp, const float* __restrict__ zp,
               int Co, int Cop, int Hout, int Wout, int act, int outfmt)
{
    constexpr int TH = 8, PAD = K / 2;
    constexpr int PR = TH + K - 1, PW = TW + K - 1;
    constexpr int NPOS = PR * PW, KK = K * K;
    constexpr int OUT_POS = TH * TW;
    constexpr int NT  = OUT_POS / 16;      // n-tiles total
    constexpr int MT  = COB / 16;          // m-tiles total
    constexpr int WN  = 4 / WM;
    constexpr int NM  = MT / WM;           // m-tiles per wave
    constexpr int NNW = NT / WN;           // n-tiles per wave
    constexpr int LDSB = NPOS * 64;
    constexpr int NELEM = NPOS * 4;
    constexpr int NE = (NELEM + 255) / 256;
    constexpr int EPI = OUT_POS * COB * 4; // epilogue tile worst case (fp32)
    constexpr int LDS_SZ = (2 * LDSB > EPI) ? 2 * LDSB : EPI;

    __shared__ __align__(16) char lds[LDS_SZ];

    const int Cin = C1 + C2;
    const int Hin = UP ? (Hout >> 1) : Hout;
    const int Win = UP ? (Wout >> 1) : Wout;
    const int NTX = Wout / TW, NTY = Hout / TH;

    const int tid = threadIdx.x;
    const int wv = tid >> 6, lane = tid & 63, l15 = lane & 15, kg = lane >> 4;
    const int bx = blockIdx.x;
    const int xt = (bx % NTX) * TW;
    const int yt = ((bx / NTX) % NTY) * TH;
    const int b  = bx / (NTX * NTY);
    const int ocb = blockIdx.y * COB;
    const int wm = wv % WM;
    const int wn = wv / WM;

    f32x4 acc[NM][NNW];
#pragma unroll
    for (int i = 0; i < NM; ++i)
#pragma unroll
        for (int t = 0; t < NNW; ++t) acc[i][t] = (f32x4){0.f, 0.f, 0.f, 0.f};

    int ipos[NNW];
#pragma unroll
    for (int t = 0; t < NNW; ++t) {
        int pos = (wn * NNW + t) * 16 + l15;
        ipos[t] = (pos / TW) * PW + (pos % TW);
    }

    // per-lane source offsets for each DMA issue (pre-swizzled channel group)
    unsigned offA[NE], offB[NE], okbits = 0;
#pragma unroll
    for (int i = 0; i < NE; ++i) {
        int e = tid + i * 256;
        if (e < NELEM) {
            int p = e >> 2;
            int g = (e & 3) ^ ((p >> 1) & 3);   // swizzled source group
            int py = p / PW, px = p % PW;
            int ly = yt + py - PAD, lx = xt + px - PAD;
            bool ok = true;
            if (REFLECT) { ly = reflect_idx(ly, Hout); lx = reflect_idx(lx, Wout); }
            else {
                ok = (ly >= 0) && (ly < Hout) && (lx >= 0) && (lx < Wout);
                if (!ok) { ly = 0; lx = 0; }
            }
            int sy = UP ? (ly >> 1) : ly;
            int sx = UP ? (lx >> 1) : lx;
            int esi = (b * Hin + sy) * Win + sx;
            offA[i] = (unsigned)(esi * C1 + g * 8);
            offB[i] = (unsigned)(esi * C2 + g * 8);
            if (ok) okbits |= (1u << i);
        }
    }

    auto issue = [&](int cb, int buf) {
        const bool inA = (cb * 32) < C1;
        const half_t* srcb = inA ? in1 + (size_t)(cb * 32)
                                 : in2 + (size_t)(cb * 32 - C1);
#pragma unroll
        for (int i = 0; i < NE; ++i) {
            const int e0 = i * 256 + wv * 64;      // wave-uniform slot base
            if (e0 < NELEM) {
                char* lb = lds + buf * LDSB + e0 * 16;
                const int e = e0 + lane;
                if (e < NELEM) {
                    unsigned off = inA ? offA[i] : offB[i];
                    const half_t* g = ((okbits >> i) & 1) ? srcb + off
                                                          : (const half_t*)zp;
                    gl_lds16(g, lb);
                }
            }
        }
    };

    const int NCB = Cin >> 5;
    const half_t* wb[NM];
#pragma unroll
    for (int i = 0; i < NM; ++i)
        wb[i] = wt + (size_t)(ocb + (wm * NM + i) * 16 + l15) * 32 + (kg << 3);

    issue(0, 0);
    int cur = 0;
    for (int cb = 0; cb < NCB; ++cb) {
        __syncthreads();                    // drains DMA -> buf[cur] ready
        if (cb + 1 < NCB) issue(cb + 1, cur ^ 1);   // next chunk in flight
        const size_t cbase = (size_t)cb * KK * Cop * 32;
        const char* lb = lds + cur * LDSB;

        // ---- software-pipelined kk loop: load kk+1 before MFMAs of kk ----
        half8 a_c[NM], b_c[NNW];
#pragma unroll
        for (int i = 0; i < NM; ++i)
            a_c[i] = *(const half8*)(wb[i] + cbase);
#pragma unroll
        for (int t = 0; t < NNW; ++t) {
            int idx = ipos[t];
            b_c[t] = *(const half8*)(lb + idx * 64 + ((kg ^ ((idx >> 1) & 3)) << 4));
        }
#pragma unroll
        for (int kk = 0; kk < KK; ++kk) {
            half8 a_n[NM], b_n[NNW];
            if (kk + 1 < KK) {
#pragma unroll
                for (int i = 0; i < NM; ++i)
                    a_n[i] = *(const half8*)(wb[i] + cbase + (size_t)(kk + 1) * Cop * 32);
                int ikk = ((kk + 1) / K) * PW + ((kk + 1) % K);
#pragma unroll
                for (int t = 0; t < NNW; ++t) {
                    int idx = ipos[t] + ikk;
                    b_n[t] = *(const half8*)(lb + idx * 64 + ((kg ^ ((idx >> 1) & 3)) << 4));
                }
            }
#pragma unroll
            for (int i = 0; i < NM; ++i)
#pragma unroll
                for (int t = 0; t < NNW; ++t)
                    acc[i][t] = __builtin_amdgcn_mfma_f32_16x16x32_f16(a_c[i], b_c[t], acc[i][t], 0, 0, 0);
            if (kk + 1 < KK) {
#pragma unroll
                for (int i = 0; i < NM; ++i) a_c[i] = a_n[i];
#pragma unroll
                for (int t = 0; t < NNW; ++t) b_c[t] = b_n[t];
            }
        }
        cur ^= 1;
    }

    // ---- epilogue ----
    if (outfmt == 1) {
        // direct fp32 NCHW store with oc guard (om convs + final conv)
#pragma unroll
        for (int i = 0; i < NM; ++i)
#pragma unroll
            for (int t = 0; t < NNW; ++t) {
                int pos = (wn * NNW + t) * 16 + l15;
                int y = yt + pos / TW, x = xt + pos % TW;
#pragma unroll
                for (int j = 0; j < 4; ++j) {
                    int oc = ocb + (wm * NM + i) * 16 + kg * 4 + j;
                    if (oc < Co) {
                        float v = acc[i][t][j] + bias[oc];
                        if (act) v = tanhf(v);
                        ((float*)outp)[(((size_t)b * Co + oc) * Hout + y) * Wout + x] = v;
                    }
                }
            }
    } else if (outfmt == 0) {
        // fp16 NHWC via LDS-staged coalesced store
        __syncthreads();
        half_t* tile = (half_t*)lds;       // OUT_POS x COB fp16
#pragma unroll
        for (int i = 0; i < NM; ++i) {
            float bv[4];
#pragma unroll
            for (int j = 0; j < 4; ++j) bv[j] = bias[ocb + (wm * NM + i) * 16 + kg * 4 + j];
#pragma unroll
            for (int t = 0; t < NNW; ++t) {
                int pos = (wn * NNW + t) * 16 + l15;
#pragma unroll
                for (int j = 0; j < 4; ++j)
                    tile[pos * COB + (wm * NM + i) * 16 + kg * 4 + j] = (half_t)(acc[i][t][j] + bv[j]);
            }
        }
        __syncthreads();
        for (int e = tid; e < OUT_POS * COB / 8; e += 256) {
            int pos = e / (COB / 8), ch = (e % (COB / 8)) * 8;
            int y = yt + pos / TW, xx = xt + pos % TW;
            short8 v = *(const short8*)(tile + pos * COB + ch);
            *(short8*)((half_t*)outp + ((size_t)(b * Hout + y) * Wout + xx) * Co + ocb + ch) = v;
        }
    } else {
        // fp32 NHWC via LDS-staged coalesced store
        __syncthreads();
        float* tile = (float*)lds;         // OUT_POS x COB fp32
#pragma unroll
        for (int i = 0; i < NM; ++i) {
            float bv[4];
#pragma unroll
            for (int j = 0; j < 4; ++j) bv[j] = bias[ocb + (wm * NM + i) * 16 + kg * 4 + j];
#pragma unroll
            for (int t = 0; t < NNW; ++t) {
                int pos = (wn * NNW + t) * 16 + l15;
#pragma unroll
                for (int j = 0; j < 4; ++j)
                    tile[pos * COB + (wm * NM + i) * 16 + kg * 4 + j] = acc[i][t][j] + bv[j];
            }
        }
        __syncthreads();
        for (int e = tid; e < OUT_POS * COB / 4; e += 256) {
            int pos = e / (COB / 4), ch = (e % (COB / 4)) * 4;
            int y = yt + pos / TW, xx = xt + pos % TW;
            f32x4 v = *(const f32x4*)(tile + pos * COB + ch);
            *(f32x4*)((float*)outp + ((size_t)(b * Hout + y) * Wout + xx) * Co + ocb + ch) = v;
        }
    }
}

// ---------------- MFMA deformable conv (one block = ALL Co for its tile) ----------------
template<int C, int MINW>
__global__ __launch_bounds__(256, MINW)
void mfma_dcn(const half_t* __restrict__ xs, const float* __restrict__ om,
              const half_t* __restrict__ wtd, const float* __restrict__ bias,
              half_t* __restrict__ outb, int H, int W)
{
    constexpr int NCK = C / 32;            // 32-ch chunks
    constexpr int NQ  = C / 4;             // channel quads
    constexpr int MT  = C / 16;            // m-tiles (Co == C)
    constexpr int NM  = MT / 4;            // m-tiles per wave
    constexpr int ITERS = 64 * NQ / 256;   // gather iters per thread per tap
    __shared__ __align__(16) char lds[NCK * 4096];
    __shared__ int   addrL[64][4];
    __shared__ float wgtL[64][4];

    const int NTX = W / 8, NTY = H / 8;
    const int tid = threadIdx.x;
    const int wv = tid >> 6, lane = tid & 63, l15 = lane & 15, kg = lane >> 4;
    const int bx = blockIdx.x;
    const int xt = (bx % NTX) * 8;
    const int yt = ((bx / NTX) % NTY) * 8;
    const int b  = bx / (NTX * NTY);
    const int HW = H * W;

    f32x4 acc[NM][4];
#pragma unroll
    for (int i = 0; i < NM; ++i)
#pragma unroll
        for (int t = 0; t < 4; ++t) acc[i][t] = (f32x4){0.f, 0.f, 0.f, 0.f};

    int boff[4];
#pragma unroll
    for (int t = 0; t < 4; ++t)
        boff[t] = (t * 16 + l15) * 64 + ((kg ^ (l15 & 3)) << 4);

    for (int k = 0; k < 9; ++k) {
        __syncthreads();               // prev MFMA reads of lds done
        if (tid < 64) {
            int pos = tid;
            int y = yt + (pos >> 3), x = xt + (pos & 7);
            size_t obase = (size_t)b * 27 * HW + (size_t)y * W + x;
            float offy = om[obase + (size_t)(2 * k) * HW];
            float offx = om[obase + (size_t)(2 * k + 1) * HW];
            float ml   = om[obase + (size_t)(18 + k) * HW];
            float mk = 1.f / (1.f + expf(-ml));
            float py = (float)(y - 1 + k / 3) + offy;
            float px = (float)(x - 1 + k % 3) + offx;
            float fy = floorf(py), fx = floorf(px);
            int y0 = (int)fy, x0 = (int)fx;
            float dy = py - fy, dx = px - fx;
            int y1 = y0 + 1, x1 = x0 + 1;
            bool vy0 = (y0 >= 0) && (y0 < H), vy1 = (y1 >= 0) && (y1 < H);
            bool vx0 = (x0 >= 0) && (x0 < W), vx1 = (x1 >= 0) && (x1 < W);
            wgtL[pos][0] = (vy0 && vx0) ? (1.f - dy) * (1.f - dx) * mk : 0.f;
            wgtL[pos][1] = (vy0 && vx1) ? (1.f - dy) * dx * mk : 0.f;
            wgtL[pos][2] = (vy1 && vx0) ? dy * (1.f - dx) * mk : 0.f;
            wgtL[pos][3] = (vy1 && vx1) ? dy * dx * mk : 0.f;
            int yc0 = min(max(y0, 0), H - 1), yc1 = min(max(y1, 0), H - 1);
            int xc0 = min(max(x0, 0), W - 1), xc1 = min(max(x1, 0), W - 1);
            addrL[pos][0] = ((b * H + yc0) * W + xc0) * C;
            addrL[pos][1] = ((b * H + yc0) * W + xc1) * C;
            addrL[pos][2] = ((b * H + yc1) * W + xc0) * C;
            addrL[pos][3] = ((b * H + yc1) * W + xc1) * C;
        }
        __syncthreads();               // tables ready
#pragma unroll
        for (int it = 0; it < ITERS; ++it) {
            int u = tid + it * 256;
            int pos = u / NQ;
            int cq = u % NQ;
            int c = cq * 4;
            float w00 = wgtL[pos][0], w01 = wgtL[pos][1];
            float w10 = wgtL[pos][2], w11 = wgtL[pos][3];
            const half_t* base = xs + c;
            uint2v q00 = *(const uint2v*)(base + addrL[pos][0]);
            uint2v q01 = *(const uint2v*)(base + addrL[pos][1]);
            uint2v q10 = *(const uint2v*)(base + addrL[pos][2]);
            uint2v q11 = *(const uint2v*)(base + addrL[pos][3]);
            float f0 = hlo(q00[0]) * w00 + hlo(q01[0]) * w01 + hlo(q10[0]) * w10 + hlo(q11[0]) * w11;
            float f1 = hhi(q00[0]) * w00 + hhi(q01[0]) * w01 + hhi(q10[0]) * w10 + hhi(q11[0]) * w11;
            float f2 = hlo(q00[1]) * w00 + hlo(q01[1]) * w01 + hlo(q10[1]) * w10 + hlo(q11[1]) * w11;
            float f3 = hhi(q00[1]) * w00 + hhi(q01[1]) * w01 + hhi(q10[1]) * w10 + hhi(q11[1]) * w11;
            uint2v r;
            r[0] = (unsigned)hbits(f0) | ((unsigned)hbits(f1) << 16);
            r[1] = (unsigned)hbits(f2) | ((unsigned)hbits(f3) << 16);
            int chunk = c >> 5, cpl = (c & 31) >> 1;
            *(uint2v*)(lds + chunk * 4096 + pos * 64 +
                       ((((cpl >> 2) ^ (pos & 3)) << 4) | ((cpl & 3) << 2))) = r;
        }
        __syncthreads();               // gathered chunk ready
#pragma unroll
        for (int cbl = 0; cbl < NCK; ++cbl) {
            int cb = k * NCK + cbl;
            half8 a[NM];
#pragma unroll
            for (int i = 0; i < NM; ++i)
                a[i] = *(const half8*)(wtd + ((size_t)cb * C + (wv * NM + i) * 16 + l15) * 32 + (kg << 3));
            half8 bf[4];
#pragma unroll
            for (int t = 0; t < 4; ++t)
                bf[t] = *(const half8*)(lds + cbl * 4096 + boff[t]);
#pragma unroll
            for (int i = 0; i < NM; ++i)
#pragma unroll
                for (int t = 0; t < 4; ++t)
                    acc[i][t] = __builtin_amdgcn_mfma_f32_16x16x32_f16(a[i], bf[t], acc[i][t], 0, 0, 0);
        }
    }

    // ---- LDS-staged coalesced epilogue (64 pos x C fp16 fits in chunk lds) ----
    float bv[NM][4];
#pragma unroll
    for (int i = 0; i < NM; ++i)
#pragma unroll
        for (int j = 0; j < 4; ++j) bv[i][j] = bias[(wv * NM + i) * 16 + kg * 4 + j];
    __syncthreads();
    half_t* tile = (half_t*)lds;
#pragma unroll
    for (int i = 0; i < NM; ++i)
#pragma unroll
        for (int t = 0; t < 4; ++t) {
            int pos = t * 16 + l15;
#pragma unroll
            for (int j = 0; j < 4; ++j)
                tile[pos * C + (wv * NM + i) * 16 + kg * 4 + j] = (half_t)(acc[i][t][j] + bv[i][j]);
        }
    __syncthreads();
    for (int e = tid; e < 64 * C / 8; e += 256) {
        int pos = e / (C / 8), ch = (e % (C / 8)) * 8;
        int y = yt + (pos >> 3), xx = xt + (pos & 7);
        short8 v = *(const short8*)(tile + pos * C + ch);
        *(short8*)(outb + ((size_t)(b * H + y) * W + xx) * C + ch) = v;
    }
}

// ---------------- InstanceNorm (NHWC), 3 kernels, vectorized ----------------
template<typename TI, int V>
__global__ void inorm_p1(const TI* __restrict__ in, float* __restrict__ part,
                         int Cc, int HW, int NS)
{
    const int CG = Cc / V, G = 256 / CG;
    const int bs = blockIdx.x, s = bs % NS, b = bs / NS;
    const int tid = threadIdx.x;
    const int cg = tid % CG, r = tid / CG;
    const int rows = HW / NS, p0 = s * rows;
    const TI* bp = in + (size_t)b * HW * Cc + (size_t)cg * V;

    float sm[V], sq[V];
#pragma unroll
    for (int j = 0; j < V; ++j) { sm[j] = 0.f; sq[j] = 0.f; }
    for (int p = p0 + r; p < p0 + rows; p += G) {
        const TI* a = bp + (size_t)p * Cc;
        if constexpr (sizeof(TI) == 2) {
            half8 hv = *(const half8*)a;
#pragma unroll
            for (int j = 0; j < V; ++j) { float v = (float)hv[j]; sm[j] += v; sq[j] += v * v; }
        } else {
            f32x4 fv = *(const f32x4*)a;
#pragma unroll
            for (int j = 0; j < V; ++j) { float v = fv[j]; sm[j] += v; sq[j] += v * v; }
        }
    }
    __shared__ float red[256 * 2 * V];
    float* my = red + tid * 2 * V;
#pragma unroll
    for (int j = 0; j < V; ++j) { my[j] = sm[j]; my[V + j] = sq[j]; }
    __syncthreads();
    for (int step = G >> 1; step > 0; step >>= 1) {
        if (r < step) {
            const float* ot = red + ((r + step) * CG + cg) * 2 * V;
#pragma unroll
            for (int j = 0; j < V; ++j) { my[j] += ot[j]; my[V + j] += ot[V + j]; }
        }
        __syncthreads();
    }
    if (r == 0) {
        float* pp = part + ((size_t)(b * NS + s) * Cc + cg * V) * 2;
#pragma unroll
        for (int j = 0; j < V; ++j) { pp[2 * j] = my[j]; pp[2 * j + 1] = my[V + j]; }
    }
}

__global__ void inorm_stats(const float* __restrict__ part, float* __restrict__ stats,
                            int Cc, int HW, int NS)
{
    int b = blockIdx.x;
    for (int c = threadIdx.x; c < Cc; c += 256) {
        float S = 0.f, Q = 0.f;
        for (int s = 0; s < NS; ++s) {
            const float* pp = part + ((size_t)(b * NS + s) * Cc + c) * 2;
            S += pp[0]; Q += pp[1];
        }
        float m = S / HW;
        float var = Q / HW - m * m;
        if (var < 0.f) var = 0.f;
        stats[(b * Cc + c) * 2]     = m;
        stats[(b * Cc + c) * 2 + 1] = rsqrtf(var + EPS);
    }
}

template<typename TI, int V>
__global__ void inorm_p2(const TI* __restrict__ in, half_t* __restrict__ out_h,
                         float* __restrict__ out_f, const float* __restrict__ resid,
                         const float* __restrict__ stats,
                         int Cc, int HW, int B, int relu)
{
    int nvec = B * HW * Cc / V;
    for (int i = blockIdx.x * 256 + threadIdx.x; i < nvec; i += gridDim.x * 256) {
        size_t E = (size_t)i * V;
        int c = (int)(E % Cc);
        int b = (int)(E / ((size_t)Cc * HW));
        float vv[V];
        if constexpr (sizeof(TI) == 2) {
            half8 hv = *(const half8*)(in + E);
#pragma unroll
            for (int j = 0; j < V; ++j) vv[j] = (float)hv[j];
        } else {
            f32x4 fv = *(const f32x4*)(in + E);
#pragma unroll
            for (int j = 0; j < V; ++j) vv[j] = fv[j];
        }
        const float* st = stats + ((size_t)b * Cc + c) * 2;
#pragma unroll
        for (int j = 0; j < V; ++j) {
            float v = (vv[j] - st[2 * j]) * st[2 * j + 1];
            if (relu) v = fmaxf(v, 0.f);
            vv[j] = v;
        }
        if (resid) {
#pragma unroll
            for (int j = 0; j < V; j += 4) {
                f32x4 rv = *(const f32x4*)(resid + E + j);
                vv[j] += rv[0]; vv[j + 1] += rv[1]; vv[j + 2] += rv[2]; vv[j + 3] += rv[3];
            }
        }
        if (out_h) {
            half8 ov = (half8)0;
#pragma unroll
            for (int j = 0; j < V; ++j) ov[j] = (half_t)vv[j];
            if constexpr (sizeof(TI) == 2) {
                *(half8*)(out_h + E) = ov;
            } else {
                for (int j = 0; j < V; ++j) out_h[E + j] = (half_t)vv[j];
            }
        }
        if (out_f) {
#pragma unroll
            for (int j = 0; j < V; j += 4) {
                f32x4 ov = { vv[j], vv[j + 1], vv[j + 2], vv[j + 3] };
                *(f32x4*)(out_f + E + j) = ov;
            }
        }
    }
}

// ---------------- offset |.| mean ----------------
__global__ void abs_sum_kernel(const float* __restrict__ om, int B, int Ctot, int HW,
                               float* __restrict__ acc)
{
    long long total = (long long)B * 18 * HW;
    float s = 0.f;
    for (long long i = (long long)blockIdx.x * blockDim.x + threadIdx.x; i < total;
         i += (long long)gridDim.x * blockDim.x) {
        int pos = (int)(i % HW);
        int c   = (int)((i / HW) % 18);
        int b   = (int)(i / ((long long)18 * HW));
        s += fabsf(om[((size_t)(b * Ctot + c)) * HW + pos]);
    }
#pragma unroll
    for (int off = 32; off > 0; off >>= 1) s += __shfl_down(s, off);
    __shared__ float ws_[4];
    int lane = threadIdx.x & 63, w = threadIdx.x >> 6;
    if (lane == 0) ws_[w] = s;
    __syncthreads();
    if (threadIdx.x == 0) {
        float t = 0.f;
        int nw = blockDim.x >> 6;
        for (int i = 0; i < nw; ++i) t += ws_[i];
        atomicAdd(acc, t);
    }
}

__global__ void zero_kernel(float* p, int n) {
    int i = blockIdx.x * 256 + threadIdx.x;
    if (i < n) p[i] = 0.f;
}

__global__ void finalize_kernel(const float* __restrict__ acc, float* __restrict__ out) {
    out[0] = 0.5f * (acc[0] / (4.f * 18.f * 128.f * 128.f)
                   + acc[1] / (4.f * 18.f * 64.f * 64.f));
}

extern "C" void kernel_launch(void* const* d_in, const int* in_sizes, int n_in,
                              void* d_out, int out_size, void* d_ws, size_t ws_size,
                              hipStream_t stream)
{
    const float* x      = (const float*)d_in[0];
    const float* skip1  = (const float*)d_in[1];
    const float* skip2  = (const float*)d_in[2];
    const float* res_w  = (const float*)d_in[3];
    const float* res_b  = (const float*)d_in[4];
    const float* w1     = (const float*)d_in[5];
    const float* b1     = (const float*)d_in[6];
    const float* w2     = (const float*)d_in[7];
    const float* b2     = (const float*)d_in[8];
    const float* w3     = (const float*)d_in[9];
    const float* b3     = (const float*)d_in[10];
    const float* off2_w = (const float*)d_in[11];
    const float* off2_b = (const float*)d_in[12];
    const float* dcn2_w = (const float*)d_in[13];
    const float* dcn2_b = (const float*)d_in[14];
    const float* off1_w = (const float*)d_in[15];
    const float* off1_b = (const float*)d_in[16];
    const float* dcn1_w = (const float*)d_in[17];
    const float* dcn1_b = (const float*)d_in[18];

    char* base = (char*)d_ws;
    size_t o = 0;
    auto alloc = [&](size_t bytes) { size_t r = o; o += (bytes + 15) & ~(size_t)15; return r; };
    half_t* x_h   = (half_t*)(base + alloc(1048576ull * 2));
    float*  x_f   = (float*)(base + alloc(1048576ull * 4));
    half_t* s1c   = (half_t*)(base + alloc(4194304ull * 2));
    half_t* s2c   = (half_t*)(base + alloc(2097152ull * 2));
    float*  scrf  = (float*)(base + alloc(1048576ull * 4));
    half_t* tB_h  = (half_t*)(base + alloc(1048576ull * 2));
    float*  cur_f = (float*)(base + alloc(1048576ull * 4));
    half_t* cur_h = (half_t*)(base + alloc(1048576ull * 2));
    half_t* out1h = (half_t*)(base + alloc(2097152ull * 2));
    half_t* pre2h = (half_t*)(base + alloc(2097152ull * 2));
    half_t* out2h = (half_t*)(base + alloc(4194304ull * 2));
    half_t* pre1h = (half_t*)(base + alloc(4194304ull * 2));
    float*  om2f  = (float*)(base + alloc(442368ull * 4));
    float*  om1f  = (float*)(base + alloc(1769472ull * 4));
    half_t* wres  = (half_t*)(base + alloc(4ull * 589824 * 2));
    half_t* w1t   = (half_t*)(base + alloc(819200ull * 2));
    half_t* w2t   = (half_t*)(base + alloc(409600ull * 2));
    half_t* off2t = (half_t*)(base + alloc(73728ull * 2));
    half_t* off1t = (half_t*)(base + alloc(36864ull * 2));
    half_t* w3t   = (half_t*)(base + alloc(100352ull * 2));
    half_t* dcn2t = (half_t*)(base + alloc(147456ull * 2));
    half_t* dcn1t = (half_t*)(base + alloc(36864ull * 2));
    float*  part  = (float*)(base + alloc(262144ull * 4));
    float*  stats = (float*)(base + alloc(2048ull * 4));
    float*  zpage = (float*)(base + alloc(4096));       // zero page for OOB DMA
    float*  acc   = (float*)(base + alloc(16));
    if (ws_size < o) return;

    float* outp = (float*)d_out;

    zero_kernel<<<dim3(5), 256, 0, stream>>>(zpage, 1026);

    // ---- converts ----
    cvt_nchw_nhwc<<<dim3(4096), 256, 0, stream>>>(x, x_h, x_f, 256, 32, 32, 1048576);
    cvt_nchw_nhwc<<<dim3(16384), 256, 0, stream>>>(skip1, s1c, nullptr, 64, 128, 128, 4194304);
    cvt_nchw_nhwc<<<dim3(8192), 256, 0, stream>>>(skip2, s2c, nullptr, 128, 64, 64, 2097152);

    // ---- weight transforms ----
    for (int j = 0; j < 4; ++j)
        wtrans_conv<<<dim3(2304), 256, 0, stream>>>(res_w + (size_t)j * 589824,
                                                    wres + (size_t)j * 589824, 256, 256, 256, 9);
    wtrans_conv<<<dim3(3200), 256, 0, stream>>>(w1, w1t, 128, 128, 256, 25);
    wtrans_conv<<<dim3(1600), 256, 0, stream>>>(w2, w2t, 64, 64, 256, 25);
    wtrans_conv<<<dim3(288), 256, 0, stream>>>(off2_w, off2t, 27, 32, 256, 9);
    wtrans_conv<<<dim3(144), 256, 0, stream>>>(off1_w, off1t, 27, 32, 128, 9);
    wtrans_conv<<<dim3(392), 256, 0, stream>>>(w3, w3t, 3, 16, 128, 49);
    wtrans_dcn<<<dim3(576), 256, 0, stream>>>(dcn2_w, dcn2t, 128, 128);
    wtrans_dcn<<<dim3(144), 256, 0, stream>>>(dcn1_w, dcn1t, 64, 64);

    // ---- residual blocks (256ch @32x32), COB=32, WM=1 -> NM=2 (512 blocks) ----
    for (int i = 0; i < 2; ++i) {
        const half_t* in_h = (i == 0) ? x_h : cur_h;
        mfma_conv<3, 0, 1, 32, 1, 8, 4><<<dim3(64, 8), 256, 0, stream>>>(
            in_h, nullptr, 256, 0, wres + (size_t)(i * 2) * 589824, res_b + (i * 2) * 256,
            scrf, zpage, 256, 256, 32, 32, 0, 2);
        inorm_p1<float, 4><<<dim3(512), 256, 0, stream>>>(scrf, part, 256, 1024, 128);
        inorm_stats<<<dim3(4), 256, 0, stream>>>(part, stats, 256, 1024, 128);
        inorm_p2<float, 4><<<dim3(1024), 256, 0, stream>>>(scrf, tB_h, nullptr, nullptr,
                                                           stats, 256, 1024, 4, 1);
        mfma_conv<3, 0, 1, 32, 1, 8, 4><<<dim3(64, 8), 256, 0, stream>>>(
            tB_h, nullptr, 256, 0, wres + (size_t)(i * 2 + 1) * 589824, res_b + (i * 2 + 1) * 256,
            scrf, zpage, 256, 256, 32, 32, 0, 2);
        inorm_p1<float, 4><<<dim3(512), 256, 0, stream>>>(scrf, part, 256, 1024, 128);
        inorm_stats<<<dim3(4), 256, 0, stream>>>(part, stats, 256, 1024, 128);
        inorm_p2<float, 4><<<dim3(1024), 256, 0, stream>>>(scrf, cur_h, cur_f,
                                                           (i == 0) ? x_f : cur_f,
                                                           stats, 256, 1024, 4, 0);
    }

    // ---- conv1: up2+refpad2+5x5 (256->128) @64x64, COB=32 WM=1 (1024 blocks) ----
    mfma_conv<5, 1, 1, 32, 1, 8, 4><<<dim3(256, 4), 256, 0, stream>>>(
        cur_h, nullptr, 256, 0, w1t, b1, out1h, zpage, 128, 128, 64, 64, 0, 0);
    inorm_p1<half_t, 8><<<dim3(512), 256, 0, stream>>>(out1h, part, 128, 4096, 128);
    inorm_stats<<<dim3(4), 256, 0, stream>>>(part, stats, 128, 4096, 128);
    inorm_p2<half_t, 8><<<dim3(1024), 256, 0, stream>>>(out1h, out1h, nullptr, nullptr,
                                                        stats, 128, 4096, 4, 1);

    // ---- om2 = 3x3 zero-pad conv on concat[out1, s2c] -> 27ch fp32 NCHW ----
    mfma_conv<3, 0, 0, 32, 1, 8, 4><<<dim3(256, 1), 256, 0, stream>>>(
        out1h, s2c, 128, 128, off2t, off2_b, om2f, zpage, 27, 32, 64, 64, 0, 1);

    // ---- pre2 = deform_conv(skip2, om2): one block per tile, all 128 oc ----
    mfma_dcn<128, 1><<<dim3(256), 256, 0, stream>>>(s2c, om2f, dcn2t, dcn2_b, pre2h, 64, 64);

    // ---- conv2: up2+refpad2+5x5 concat[pre2,out1] (256->64) @128x128,
    //      COB=64 WM=1 TW=8 -> NM=4, grid 1024 (4 blocks/CU) ----
    mfma_conv<5, 1, 1, 64, 1, 8, 4><<<dim3(1024, 1), 256, 0, stream>>>(
        pre2h, out1h, 128, 128, w2t, b2, out2h, zpage, 64, 64, 128, 128, 0, 0);
    inorm_p1<half_t, 8><<<dim3(1024), 256, 0, stream>>>(out2h, part, 64, 16384, 256);
    inorm_stats<<<dim3(4), 256, 0, stream>>>(part, stats, 64, 16384, 256);
    inorm_p2<half_t, 8><<<dim3(2048), 256, 0, stream>>>(out2h, out2h, nullptr, nullptr,
                                                        stats, 64, 16384, 4, 1);

    // ---- om1 = 3x3 zero-pad conv on concat[out2, s1c] -> 27ch fp32 NCHW ----
    mfma_conv<3, 0, 0, 32, 1, 8, 4><<<dim3(1024, 1), 256, 0, stream>>>(
        out2h, s1c, 64, 64, off1t, off1_b, om1f, zpage, 27, 32, 128, 128, 0, 1);

    // ---- pre1 = deform_conv(skip1, om1): one block per tile, all 64 oc ----
    mfma_dcn<64, 2><<<dim3(1024), 256, 0, stream>>>(s1c, om1f, dcn1t, dcn1_b, pre1h, 128, 128);

    // ---- final: 7x7 refpad3 concat[pre1,out2] -> 3ch fp32 NCHW + tanh ----
    mfma_conv<7, 0, 1, 16, 1, 8, 4><<<dim3(1024, 1), 256, 0, stream>>>(
        pre1h, out2h, 64, 64, w3t, b3, outp, zpage, 3, 16, 128, 128, 1, 1);

    // ---- offset_sum ----
    abs_sum_kernel<<<dim3(256), 256, 0, stream>>>(om1f, 4, 27, 16384, acc + 0);
    abs_sum_kernel<<<dim3(256), 256, 0, stream>>>(om2f, 4, 27, 4096, acc + 1);
    finalize_kernel<<<dim3(1), dim3(1), 0, stream>>>(acc, outp + 196608);
}

// Round 15
// 1055.641 us; speedup vs baseline: 1.7658x; 1.7658x over previous
//
#include <hip/hip_runtime.h>
#include <cmath>

#define EPS 1e-5f

typedef _Float16 half_t;
typedef __attribute__((ext_vector_type(8))) _Float16 half8;
typedef __attribute__((ext_vector_type(8))) short short8;
typedef __attribute__((ext_vector_type(4))) float f32x4;
typedef __attribute__((ext_vector_type(2))) unsigned int uint2v;

__device__ __forceinline__ int reflect_idx(int p, int S) {
    if (p < 0) p = -p;
    if (p >= S) p = 2 * S - 2 - p;
    return p;
}
__device__ __forceinline__ float hlo(unsigned v) {
    return (float)__builtin_bit_cast(half_t, (unsigned short)(v & 0xffffu));
}
__device__ __forceinline__ float hhi(unsigned v) {
    return (float)__builtin_bit_cast(half_t, (unsigned short)(v >> 16));
}
__device__ __forceinline__ unsigned short hbits(float f) {
    return __builtin_bit_cast(unsigned short, (half_t)f);
}

// async global->LDS DMA, 16B per lane; lds dest = wave-uniform base + lane*16
__device__ __forceinline__ void gl_lds16(const half_t* g, char* l) {
    __builtin_amdgcn_global_load_lds(
        (const __attribute__((address_space(1))) unsigned int*)g,
        (__attribute__((address_space(3))) unsigned int*)l, 16, 0, 0);
}

// ---------------- weight transforms (fp32 -> fp16) ----------------
// conv weights [Co][Cin][KK] -> [cb][kk][Cop][32] where c = cb*32 + cl.
__global__ void wtrans_conv(const float* __restrict__ w, half_t* __restrict__ wt,
                            int Co, int Cop, int Cin, int KK)
{
    int i = blockIdx.x * 256 + threadIdx.x;
    int total = KK * Cop * Cin;
    if (i >= total) return;
    int cl = i & 31;
    int oc = (i >> 5) % Cop;
    int rest = (i >> 5) / Cop;     // cb*KK + kk
    int kk = rest % KK;
    int cb = rest / KK;
    int c = (cb << 5) + cl;
    float v = (oc < Co) ? w[((size_t)oc * Cin + c) * KK + kk] : 0.f;
    wt[i] = (half_t)v;
}

// dcn weights [Co][Cin][9] -> [cb][Co][32] with kidx = k*Cin + c = cb*32 + cl
__global__ void wtrans_dcn(const float* __restrict__ w, half_t* __restrict__ wt,
                           int Co, int Cin)
{
    int i = blockIdx.x * 256 + threadIdx.x;
    int total = Co * 9 * Cin;
    if (i >= total) return;
    int cl = i & 31;
    int oc = (i >> 5) % Co;
    int cb = (i >> 5) / Co;
    int kidx = (cb << 5) + cl;
    int k = kidx / Cin, c = kidx % Cin;
    wt[i] = (half_t)w[((size_t)oc * Cin + c) * 9 + k];
}

// ---------------- NCHW fp32 -> NHWC fp16 (+ optional fp32 NHWC copy) ----------------
__global__ void cvt_nchw_nhwc(const float* __restrict__ in, half_t* __restrict__ out,
                              float* __restrict__ outf, int C, int H, int W, int total)
{
    int i = blockIdx.x * 256 + threadIdx.x;
    if (i >= total) return;
    int c = i % C;
    int x = (i / C) % W;
    int y = (i / (C * W)) % H;
    int b = i / (C * W * H);
    float v = in[(((size_t)b * C + c) * H + y) * W + x];
    out[i] = (half_t)v;
    if (outf) outf[i] = v;
}

// ---------------- MFMA implicit-GEMM conv ----------------
// TH=8 x TW positions x COB ocs per block, 4 waves arranged WM x (4/WM).
// Wave register-blocks NM oc-tiles x NNW pos-tiles. MINW picks the VGPR
// budget (256/MINW/..): keep pipeline regs (~8*(NM+NNW)+4*NM*NNW+misc) under it.
// outfmt: 0 = fp16 NHWC (stride Co), 1 = fp32 NCHW (guarded), 2 = fp32 NHWC.
template<int K, int UP, int REFLECT, int COB, int WM, int TW, int MINW>
__global__ __launch_bounds__(256, MINW)
void mfma_conv(const half_t* __restrict__ in1, const half_t* __restrict__ in2,
               int C1, int C2,
               const half_t* __restrict__ wt, const float* __restrict__ bias,
               void* __restrict__ outp, const float* __restrict__ zp,
               int Co, int Cop, int Hout, int Wout, int act, int outfmt)
{
    constexpr int TH = 8, PAD = K / 2;
    constexpr int PR = TH + K - 1, PW = TW + K - 1;
    constexpr int NPOS = PR * PW, KK = K * K;
    constexpr int OUT_POS = TH * TW;
    constexpr int NT  = OUT_POS / 16;      // n-tiles total
    constexpr int MT  = COB / 16;          // m-tiles total
    constexpr int WN  = 4 / WM;
    constexpr int NM  = MT / WM;           // m-tiles per wave
    constexpr int NNW = NT / WN;           // n-tiles per wave
    constexpr int LDSB = NPOS * 64;
    constexpr int NELEM = NPOS * 4;
    constexpr int NE = (NELEM + 255) / 256;
    constexpr int EPI = OUT_POS * COB * 4; // epilogue tile worst case (fp32)
    constexpr int LDS_SZ = (2 * LDSB > EPI) ? 2 * LDSB : EPI;

    __shared__ __align__(16) char lds[LDS_SZ];

    const int Cin = C1 + C2;
    const int Hin = UP ? (Hout >> 1) : Hout;
    const int Win = UP ? (Wout >> 1) : Wout;
    const int NTX = Wout / TW, NTY = Hout / TH;

    const int tid = threadIdx.x;
    const int wv = tid >> 6, lane = tid & 63, l15 = lane & 15, kg = lane >> 4;
    const int bx = blockIdx.x;
    const int xt = (bx % NTX) * TW;
    const int yt = ((bx / NTX) % NTY) * TH;
    const int b  = bx / (NTX * NTY);
    const int ocb = blockIdx.y * COB;
    const int wm = wv % WM;
    const int wn = wv / WM;

    f32x4 acc[NM][NNW];
#pragma unroll
    for (int i = 0; i < NM; ++i)
#pragma unroll
        for (int t = 0; t < NNW; ++t) acc[i][t] = (f32x4){0.f, 0.f, 0.f, 0.f};

    int ipos[NNW];
#pragma unroll
    for (int t = 0; t < NNW; ++t) {
        int pos = (wn * NNW + t) * 16 + l15;
        ipos[t] = (pos / TW) * PW + (pos % TW);
    }

    // per-lane source offsets for each DMA issue (pre-swizzled channel group)
    unsigned offA[NE], offB[NE], okbits = 0;
#pragma unroll
    for (int i = 0; i < NE; ++i) {
        int e = tid + i * 256;
        if (e < NELEM) {
            int p = e >> 2;
            int g = (e & 3) ^ ((p >> 1) & 3);   // swizzled source group
            int py = p / PW, px = p % PW;
            int ly = yt + py - PAD, lx = xt + px - PAD;
            bool ok = true;
            if (REFLECT) { ly = reflect_idx(ly, Hout); lx = reflect_idx(lx, Wout); }
            else {
                ok = (ly >= 0) && (ly < Hout) && (lx >= 0) && (lx < Wout);
                if (!ok) { ly = 0; lx = 0; }
            }
            int sy = UP ? (ly >> 1) : ly;
            int sx = UP ? (lx >> 1) : lx;
            int esi = (b * Hin + sy) * Win + sx;
            offA[i] = (unsigned)(esi * C1 + g * 8);
            offB[i] = (unsigned)(esi * C2 + g * 8);
            if (ok) okbits |= (1u << i);
        }
    }

    auto issue = [&](int cb, int buf) {
        const bool inA = (cb * 32) < C1;
        const half_t* srcb = inA ? in1 + (size_t)(cb * 32)
                                 : in2 + (size_t)(cb * 32 - C1);
#pragma unroll
        for (int i = 0; i < NE; ++i) {
            const int e0 = i * 256 + wv * 64;      // wave-uniform slot base
            if (e0 < NELEM) {
                char* lb = lds + buf * LDSB + e0 * 16;
                const int e = e0 + lane;
                if (e < NELEM) {
                    unsigned off = inA ? offA[i] : offB[i];
                    const half_t* g = ((okbits >> i) & 1) ? srcb + off
                                                          : (const half_t*)zp;
                    gl_lds16(g, lb);
                }
            }
        }
    };

    const int NCB = Cin >> 5;
    const half_t* wb[NM];
#pragma unroll
    for (int i = 0; i < NM; ++i)
        wb[i] = wt + (size_t)(ocb + (wm * NM + i) * 16 + l15) * 32 + (kg << 3);

    issue(0, 0);
    int cur = 0;
    for (int cb = 0; cb < NCB; ++cb) {
        __syncthreads();                    // drains DMA -> buf[cur] ready
        if (cb + 1 < NCB) issue(cb + 1, cur ^ 1);   // next chunk in flight
        const size_t cbase = (size_t)cb * KK * Cop * 32;
        const char* lb = lds + cur * LDSB;

        // ---- software-pipelined kk loop: load kk+1 before MFMAs of kk ----
        half8 a_c[NM], b_c[NNW];
#pragma unroll
        for (int i = 0; i < NM; ++i)
            a_c[i] = *(const half8*)(wb[i] + cbase);
#pragma unroll
        for (int t = 0; t < NNW; ++t) {
            int idx = ipos[t];
            b_c[t] = *(const half8*)(lb + idx * 64 + ((kg ^ ((idx >> 1) & 3)) << 4));
        }
#pragma unroll
        for (int kk = 0; kk < KK; ++kk) {
            half8 a_n[NM], b_n[NNW];
            if (kk + 1 < KK) {
#pragma unroll
                for (int i = 0; i < NM; ++i)
                    a_n[i] = *(const half8*)(wb[i] + cbase + (size_t)(kk + 1) * Cop * 32);
                int ikk = ((kk + 1) / K) * PW + ((kk + 1) % K);
#pragma unroll
                for (int t = 0; t < NNW; ++t) {
                    int idx = ipos[t] + ikk;
                    b_n[t] = *(const half8*)(lb + idx * 64 + ((kg ^ ((idx >> 1) & 3)) << 4));
                }
            }
#pragma unroll
            for (int i = 0; i < NM; ++i)
#pragma unroll
                for (int t = 0; t < NNW; ++t)
                    acc[i][t] = __builtin_amdgcn_mfma_f32_16x16x32_f16(a_c[i], b_c[t], acc[i][t], 0, 0, 0);
            if (kk + 1 < KK) {
#pragma unroll
                for (int i = 0; i < NM; ++i) a_c[i] = a_n[i];
#pragma unroll
                for (int t = 0; t < NNW; ++t) b_c[t] = b_n[t];
            }
        }
        cur ^= 1;
    }

    // ---- epilogue ----
    if (outfmt == 1) {
        // direct fp32 NCHW store with oc guard (om convs + final conv)
#pragma unroll
        for (int i = 0; i < NM; ++i)
#pragma unroll
            for (int t = 0; t < NNW; ++t) {
                int pos = (wn * NNW + t) * 16 + l15;
                int y = yt + pos / TW, x = xt + pos % TW;
#pragma unroll
                for (int j = 0; j < 4; ++j) {
                    int oc = ocb + (wm * NM + i) * 16 + kg * 4 + j;
                    if (oc < Co) {
                        float v = acc[i][t][j] + bias[oc];
                        if (act) v = tanhf(v);
                        ((float*)outp)[(((size_t)b * Co + oc) * Hout + y) * Wout + x] = v;
                    }
                }
            }
    } else if (outfmt == 0) {
        // fp16 NHWC via LDS-staged coalesced store
        __syncthreads();
        half_t* tile = (half_t*)lds;       // OUT_POS x COB fp16
#pragma unroll
        for (int i = 0; i < NM; ++i) {
            float bv[4];
#pragma unroll
            for (int j = 0; j < 4; ++j) bv[j] = bias[ocb + (wm * NM + i) * 16 + kg * 4 + j];
#pragma unroll
            for (int t = 0; t < NNW; ++t) {
                int pos = (wn * NNW + t) * 16 + l15;
#pragma unroll
                for (int j = 0; j < 4; ++j)
                    tile[pos * COB + (wm * NM + i) * 16 + kg * 4 + j] = (half_t)(acc[i][t][j] + bv[j]);
            }
        }
        __syncthreads();
        for (int e = tid; e < OUT_POS * COB / 8; e += 256) {
            int pos = e / (COB / 8), ch = (e % (COB / 8)) * 8;
            int y = yt + pos / TW, xx = xt + pos % TW;
            short8 v = *(const short8*)(tile + pos * COB + ch);
            *(short8*)((half_t*)outp + ((size_t)(b * Hout + y) * Wout + xx) * Co + ocb + ch) = v;
        }
    } else {
        // fp32 NHWC via LDS-staged coalesced store
        __syncthreads();
        float* tile = (float*)lds;         // OUT_POS x COB fp32
#pragma unroll
        for (int i = 0; i < NM; ++i) {
            float bv[4];
#pragma unroll
            for (int j = 0; j < 4; ++j) bv[j] = bias[ocb + (wm * NM + i) * 16 + kg * 4 + j];
#pragma unroll
            for (int t = 0; t < NNW; ++t) {
                int pos = (wn * NNW + t) * 16 + l15;
#pragma unroll
                for (int j = 0; j < 4; ++j)
                    tile[pos * COB + (wm * NM + i) * 16 + kg * 4 + j] = acc[i][t][j] + bv[j];
            }
        }
        __syncthreads();
        for (int e = tid; e < OUT_POS * COB / 4; e += 256) {
            int pos = e / (COB / 4), ch = (e % (COB / 4)) * 4;
            int y = yt + pos / TW, xx = xt + pos % TW;
            f32x4 v = *(const f32x4*)(tile + pos * COB + ch);
            *(f32x4*)((float*)outp + ((size_t)(b * Hout + y) * Wout + xx) * Co + ocb + ch) = v;
        }
    }
}

// ---------------- MFMA deformable conv (one block = ALL Co for its tile) ----------------
template<int C, int MINW>
__global__ __launch_bounds__(256, MINW)
void mfma_dcn(const half_t* __restrict__ xs, const float* __restrict__ om,
              const half_t* __restrict__ wtd, const float* __restrict__ bias,
              half_t* __restrict__ outb, int H, int W)
{
    constexpr int NCK = C / 32;            // 32-ch chunks
    constexpr int NQ  = C / 4;             // channel quads
    constexpr int MT  = C / 16;            // m-tiles (Co == C)
    constexpr int NM  = MT / 4;            // m-tiles per wave
    constexpr int ITERS = 64 * NQ / 256;   // gather iters per thread per tap
    __shared__ __align__(16) char lds[NCK * 4096];
    __shared__ int   addrL[64][4];
    __shared__ float wgtL[64][4];

    const int NTX = W / 8, NTY = H / 8;
    const int tid = threadIdx.x;
    const int wv = tid >> 6, lane = tid & 63, l15 = lane & 15, kg = lane >> 4;
    const int bx = blockIdx.x;
    const int xt = (bx % NTX) * 8;
    const int yt = ((bx / NTX) % NTY) * 8;
    const int b  = bx / (NTX * NTY);
    const int HW = H * W;

    f32x4 acc[NM][4];
#pragma unroll
    for (int i = 0; i < NM; ++i)
#pragma unroll
        for (int t = 0; t < 4; ++t) acc[i][t] = (f32x4){0.f, 0.f, 0.f, 0.f};

    int boff[4];
#pragma unroll
    for (int t = 0; t < 4; ++t)
        boff[t] = (t * 16 + l15) * 64 + ((kg ^ (l15 & 3)) << 4);

    for (int k = 0; k < 9; ++k) {
        __syncthreads();               // prev MFMA reads of lds done
        if (tid < 64) {
            int pos = tid;
            int y = yt + (pos >> 3), x = xt + (pos & 7);
            size_t obase = (size_t)b * 27 * HW + (size_t)y * W + x;
            float offy = om[obase + (size_t)(2 * k) * HW];
            float offx = om[obase + (size_t)(2 * k + 1) * HW];
            float ml   = om[obase + (size_t)(18 + k) * HW];
            float mk = 1.f / (1.f + expf(-ml));
            float py = (float)(y - 1 + k / 3) + offy;
            float px = (float)(x - 1 + k % 3) + offx;
            float fy = floorf(py), fx = floorf(px);
            int y0 = (int)fy, x0 = (int)fx;
            float dy = py - fy, dx = px - fx;
            int y1 = y0 + 1, x1 = x0 + 1;
            bool vy0 = (y0 >= 0) && (y0 < H), vy1 = (y1 >= 0) && (y1 < H);
            bool vx0 = (x0 >= 0) && (x0 < W), vx1 = (x1 >= 0) && (x1 < W);
            wgtL[pos][0] = (vy0 && vx0) ? (1.f - dy) * (1.f - dx) * mk : 0.f;
            wgtL[pos][1] = (vy0 && vx1) ? (1.f - dy) * dx * mk : 0.f;
            wgtL[pos][2] = (vy1 && vx0) ? dy * (1.f - dx) * mk : 0.f;
            wgtL[pos][3] = (vy1 && vx1) ? dy * dx * mk : 0.f;
            int yc0 = min(max(y0, 0), H - 1), yc1 = min(max(y1, 0), H - 1);
            int xc0 = min(max(x0, 0), W - 1), xc1 = min(max(x1, 0), W - 1);
            addrL[pos][0] = ((b * H + yc0) * W + xc0) * C;
            addrL[pos][1] = ((b * H + yc0) * W + xc1) * C;
            addrL[pos][2] = ((b * H + yc1) * W + xc0) * C;
            addrL[pos][3] = ((b * H + yc1) * W + xc1) * C;
        }
        __syncthreads();               // tables ready
#pragma unroll
        for (int it = 0; it < ITERS; ++it) {
            int u = tid + it * 256;
            int pos = u / NQ;
            int cq = u % NQ;
            int c = cq * 4;
            float w00 = wgtL[pos][0], w01 = wgtL[pos][1];
            float w10 = wgtL[pos][2], w11 = wgtL[pos][3];
            const half_t* base = xs + c;
            uint2v q00 = *(const uint2v*)(base + addrL[pos][0]);
            uint2v q01 = *(const uint2v*)(base + addrL[pos][1]);
            uint2v q10 = *(const uint2v*)(base + addrL[pos][2]);
            uint2v q11 = *(const uint2v*)(base + addrL[pos][3]);
            float f0 = hlo(q00[0]) * w00 + hlo(q01[0]) * w01 + hlo(q10[0]) * w10 + hlo(q11[0]) * w11;
            float f1 = hhi(q00[0]) * w00 + hhi(q01[0]) * w01 + hhi(q10[0]) * w10 + hhi(q11[0]) * w11;
            float f2 = hlo(q00[1]) * w00 + hlo(q01[1]) * w01 + hlo(q10[1]) * w10 + hlo(q11[1]) * w11;
            float f3 = hhi(q00[1]) * w00 + hhi(q01[1]) * w01 + hhi(q10[1]) * w10 + hhi(q11[1]) * w11;
            uint2v r;
            r[0] = (unsigned)hbits(f0) | ((unsigned)hbits(f1) << 16);
            r[1] = (unsigned)hbits(f2) | ((unsigned)hbits(f3) << 16);
            int chunk = c >> 5, cpl = (c & 31) >> 1;
            *(uint2v*)(lds + chunk * 4096 + pos * 64 +
                       ((((cpl >> 2) ^ (pos & 3)) << 4) | ((cpl & 3) << 2))) = r;
        }
        __syncthreads();               // gathered chunk ready
#pragma unroll
        for (int cbl = 0; cbl < NCK; ++cbl) {
            int cb = k * NCK + cbl;
            half8 a[NM];
#pragma unroll
            for (int i = 0; i < NM; ++i)
                a[i] = *(const half8*)(wtd + ((size_t)cb * C + (wv * NM + i) * 16 + l15) * 32 + (kg << 3));
            half8 bf[4];
#pragma unroll
            for (int t = 0; t < 4; ++t)
                bf[t] = *(const half8*)(lds + cbl * 4096 + boff[t]);
#pragma unroll
            for (int i = 0; i < NM; ++i)
#pragma unroll
                for (int t = 0; t < 4; ++t)
                    acc[i][t] = __builtin_amdgcn_mfma_f32_16x16x32_f16(a[i], bf[t], acc[i][t], 0, 0, 0);
        }
    }

    // ---- LDS-staged coalesced epilogue (64 pos x C fp16 fits in chunk lds) ----
    float bv[NM][4];
#pragma unroll
    for (int i = 0; i < NM; ++i)
#pragma unroll
        for (int j = 0; j < 4; ++j) bv[i][j] = bias[(wv * NM + i) * 16 + kg * 4 + j];
    __syncthreads();
    half_t* tile = (half_t*)lds;
#pragma unroll
    for (int i = 0; i < NM; ++i)
#pragma unroll
        for (int t = 0; t < 4; ++t) {
            int pos = t * 16 + l15;
#pragma unroll
            for (int j = 0; j < 4; ++j)
                tile[pos * C + (wv * NM + i) * 16 + kg * 4 + j] = (half_t)(acc[i][t][j] + bv[i][j]);
        }
    __syncthreads();
    for (int e = tid; e < 64 * C / 8; e += 256) {
        int pos = e / (C / 8), ch = (e % (C / 8)) * 8;
        int y = yt + (pos >> 3), xx = xt + (pos & 7);
        short8 v = *(const short8*)(tile + pos * C + ch);
        *(short8*)(outb + ((size_t)(b * H + y) * W + xx) * C + ch) = v;
    }
}

// ---------------- InstanceNorm (NHWC), 3 kernels, vectorized ----------------
template<typename TI, int V>
__global__ void inorm_p1(const TI* __restrict__ in, float* __restrict__ part,
                         int Cc, int HW, int NS)
{
    const int CG = Cc / V, G = 256 / CG;
    const int bs = blockIdx.x, s = bs % NS, b = bs / NS;
    const int tid = threadIdx.x;
    const int cg = tid % CG, r = tid / CG;
    const int rows = HW / NS, p0 = s * rows;
    const TI* bp = in + (size_t)b * HW * Cc + (size_t)cg * V;

    float sm[V], sq[V];
#pragma unroll
    for (int j = 0; j < V; ++j) { sm[j] = 0.f; sq[j] = 0.f; }
    for (int p = p0 + r; p < p0 + rows; p += G) {
        const TI* a = bp + (size_t)p * Cc;
        if constexpr (sizeof(TI) == 2) {
            half8 hv = *(const half8*)a;
#pragma unroll
            for (int j = 0; j < V; ++j) { float v = (float)hv[j]; sm[j] += v; sq[j] += v * v; }
        } else {
            f32x4 fv = *(const f32x4*)a;
#pragma unroll
            for (int j = 0; j < V; ++j) { float v = fv[j]; sm[j] += v; sq[j] += v * v; }
        }
    }
    __shared__ float red[256 * 2 * V];
    float* my = red + tid * 2 * V;
#pragma unroll
    for (int j = 0; j < V; ++j) { my[j] = sm[j]; my[V + j] = sq[j]; }
    __syncthreads();
    for (int step = G >> 1; step > 0; step >>= 1) {
        if (r < step) {
            const float* ot = red + ((r + step) * CG + cg) * 2 * V;
#pragma unroll
            for (int j = 0; j < V; ++j) { my[j] += ot[j]; my[V + j] += ot[V + j]; }
        }
        __syncthreads();
    }
    if (r == 0) {
        float* pp = part + ((size_t)(b * NS + s) * Cc + cg * V) * 2;
#pragma unroll
        for (int j = 0; j < V; ++j) { pp[2 * j] = my[j]; pp[2 * j + 1] = my[V + j]; }
    }
}

__global__ void inorm_stats(const float* __restrict__ part, float* __restrict__ stats,
                            int Cc, int HW, int NS)
{
    int b = blockIdx.x;
    for (int c = threadIdx.x; c < Cc; c += 256) {
        float S = 0.f, Q = 0.f;
        for (int s = 0; s < NS; ++s) {
            const float* pp = part + ((size_t)(b * NS + s) * Cc + c) * 2;
            S += pp[0]; Q += pp[1];
        }
        float m = S / HW;
        float var = Q / HW - m * m;
        if (var < 0.f) var = 0.f;
        stats[(b * Cc + c) * 2]     = m;
        stats[(b * Cc + c) * 2 + 1] = rsqrtf(var + EPS);
    }
}

template<typename TI, int V>
__global__ void inorm_p2(const TI* __restrict__ in, half_t* __restrict__ out_h,
                         float* __restrict__ out_f, const float* __restrict__ resid,
                         const float* __restrict__ stats,
                         int Cc, int HW, int B, int relu)
{
    int nvec = B * HW * Cc / V;
    for (int i = blockIdx.x * 256 + threadIdx.x; i < nvec; i += gridDim.x * 256) {
        size_t E = (size_t)i * V;
        int c = (int)(E % Cc);
        int b = (int)(E / ((size_t)Cc * HW));
        float vv[V];
        if constexpr (sizeof(TI) == 2) {
            half8 hv = *(const half8*)(in + E);
#pragma unroll
            for (int j = 0; j < V; ++j) vv[j] = (float)hv[j];
        } else {
            f32x4 fv = *(const f32x4*)(in + E);
#pragma unroll
            for (int j = 0; j < V; ++j) vv[j] = fv[j];
        }
        const float* st = stats + ((size_t)b * Cc + c) * 2;
#pragma unroll
        for (int j = 0; j < V; ++j) {
            float v = (vv[j] - st[2 * j]) * st[2 * j + 1];
            if (relu) v = fmaxf(v, 0.f);
            vv[j] = v;
        }
        if (resid) {
#pragma unroll
            for (int j = 0; j < V; j += 4) {
                f32x4 rv = *(const f32x4*)(resid + E + j);
                vv[j] += rv[0]; vv[j + 1] += rv[1]; vv[j + 2] += rv[2]; vv[j + 3] += rv[3];
            }
        }
        if (out_h) {
            half8 ov = (half8)0;
#pragma unroll
            for (int j = 0; j < V; ++j) ov[j] = (half_t)vv[j];
            if constexpr (sizeof(TI) == 2) {
                *(half8*)(out_h + E) = ov;
            } else {
                for (int j = 0; j < V; ++j) out_h[E + j] = (half_t)vv[j];
            }
        }
        if (out_f) {
#pragma unroll
            for (int j = 0; j < V; j += 4) {
                f32x4 ov = { vv[j], vv[j + 1], vv[j + 2], vv[j + 3] };
                *(f32x4*)(out_f + E + j) = ov;
            }
        }
    }
}

// ---------------- offset |.| mean ----------------
__global__ void abs_sum_kernel(const float* __restrict__ om, int B, int Ctot, int HW,
                               float* __restrict__ acc)
{
    long long total = (long long)B * 18 * HW;
    float s = 0.f;
    for (long long i = (long long)blockIdx.x * blockDim.x + threadIdx.x; i < total;
         i += (long long)gridDim.x * blockDim.x) {
        int pos = (int)(i % HW);
        int c   = (int)((i / HW) % 18);
        int b   = (int)(i / ((long long)18 * HW));
        s += fabsf(om[((size_t)(b * Ctot + c)) * HW + pos]);
    }
#pragma unroll
    for (int off = 32; off > 0; off >>= 1) s += __shfl_down(s, off);
    __shared__ float ws_[4];
    int lane = threadIdx.x & 63, w = threadIdx.x >> 6;
    if (lane == 0) ws_[w] = s;
    __syncthreads();
    if (threadIdx.x == 0) {
        float t = 0.f;
        int nw = blockDim.x >> 6;
        for (int i = 0; i < nw; ++i) t += ws_[i];
        atomicAdd(acc, t);
    }
}

__global__ void zero_kernel(float* p, int n) {
    int i = blockIdx.x * 256 + threadIdx.x;
    if (i < n) p[i] = 0.f;
}

__global__ void finalize_kernel(const float* __restrict__ acc, float* __restrict__ out) {
    out[0] = 0.5f * (acc[0] / (4.f * 18.f * 128.f * 128.f)
                   + acc[1] / (4.f * 18.f * 64.f * 64.f));
}

extern "C" void kernel_launch(void* const* d_in, const int* in_sizes, int n_in,
                              void* d_out, int out_size, void* d_ws, size_t ws_size,
                              hipStream_t stream)
{
    const float* x      = (const float*)d_in[0];
    const float* skip1  = (const float*)d_in[1];
    const float* skip2  = (const float*)d_in[2];
    const float* res_w  = (const float*)d_in[3];
    const float* res_b  = (const float*)d_in[4];
    const float* w1     = (const float*)d_in[5];
    const float* b1     = (const float*)d_in[6];
    const float* w2     = (const float*)d_in[7];
    const float* b2     = (const float*)d_in[8];
    const float* w3     = (const float*)d_in[9];
    const float* b3     = (const float*)d_in[10];
    const float* off2_w = (const float*)d_in[11];
    const float* off2_b = (const float*)d_in[12];
    const float* dcn2_w = (const float*)d_in[13];
    const float* dcn2_b = (const float*)d_in[14];
    const float* off1_w = (const float*)d_in[15];
    const float* off1_b = (const float*)d_in[16];
    const float* dcn1_w = (const float*)d_in[17];
    const float* dcn1_b = (const float*)d_in[18];

    char* base = (char*)d_ws;
    size_t o = 0;
    auto alloc = [&](size_t bytes) { size_t r = o; o += (bytes + 15) & ~(size_t)15; return r; };
    half_t* x_h   = (half_t*)(base + alloc(1048576ull * 2));
    float*  x_f   = (float*)(base + alloc(1048576ull * 4));
    half_t* s1c   = (half_t*)(base + alloc(4194304ull * 2));
    half_t* s2c   = (half_t*)(base + alloc(2097152ull * 2));
    float*  scrf  = (float*)(base + alloc(1048576ull * 4));
    half_t* tB_h  = (half_t*)(base + alloc(1048576ull * 2));
    float*  cur_f = (float*)(base + alloc(1048576ull * 4));
    half_t* cur_h = (half_t*)(base + alloc(1048576ull * 2));
    half_t* out1h = (half_t*)(base + alloc(2097152ull * 2));
    half_t* pre2h = (half_t*)(base + alloc(2097152ull * 2));
    half_t* out2h = (half_t*)(base + alloc(4194304ull * 2));
    half_t* pre1h = (half_t*)(base + alloc(4194304ull * 2));
    float*  om2f  = (float*)(base + alloc(442368ull * 4));
    float*  om1f  = (float*)(base + alloc(1769472ull * 4));
    half_t* wres  = (half_t*)(base + alloc(4ull * 589824 * 2));
    half_t* w1t   = (half_t*)(base + alloc(819200ull * 2));
    half_t* w2t   = (half_t*)(base + alloc(409600ull * 2));
    half_t* off2t = (half_t*)(base + alloc(73728ull * 2));
    half_t* off1t = (half_t*)(base + alloc(36864ull * 2));
    half_t* w3t   = (half_t*)(base + alloc(100352ull * 2));
    half_t* dcn2t = (half_t*)(base + alloc(147456ull * 2));
    half_t* dcn1t = (half_t*)(base + alloc(36864ull * 2));
    float*  part  = (float*)(base + alloc(262144ull * 4));
    float*  stats = (float*)(base + alloc(2048ull * 4));
    float*  zpage = (float*)(base + alloc(4096));       // zero page for OOB DMA
    float*  acc   = (float*)(base + alloc(16));
    if (ws_size < o) return;

    float* outp = (float*)d_out;

    zero_kernel<<<dim3(5), 256, 0, stream>>>(zpage, 1026);

    // ---- converts ----
    cvt_nchw_nhwc<<<dim3(4096), 256, 0, stream>>>(x, x_h, x_f, 256, 32, 32, 1048576);
    cvt_nchw_nhwc<<<dim3(16384), 256, 0, stream>>>(skip1, s1c, nullptr, 64, 128, 128, 4194304);
    cvt_nchw_nhwc<<<dim3(8192), 256, 0, stream>>>(skip2, s2c, nullptr, 128, 64, 64, 2097152);

    // ---- weight transforms ----
    for (int j = 0; j < 4; ++j)
        wtrans_conv<<<dim3(2304), 256, 0, stream>>>(res_w + (size_t)j * 589824,
                                                    wres + (size_t)j * 589824, 256, 256, 256, 9);
    wtrans_conv<<<dim3(3200), 256, 0, stream>>>(w1, w1t, 128, 128, 256, 25);
    wtrans_conv<<<dim3(1600), 256, 0, stream>>>(w2, w2t, 64, 64, 256, 25);
    wtrans_conv<<<dim3(288), 256, 0, stream>>>(off2_w, off2t, 27, 32, 256, 9);
    wtrans_conv<<<dim3(144), 256, 0, stream>>>(off1_w, off1t, 27, 32, 128, 9);
    wtrans_conv<<<dim3(392), 256, 0, stream>>>(w3, w3t, 3, 16, 128, 49);
    wtrans_dcn<<<dim3(576), 256, 0, stream>>>(dcn2_w, dcn2t, 128, 128);
    wtrans_dcn<<<dim3(144), 256, 0, stream>>>(dcn1_w, dcn1t, 64, 64);

    // ---- residual blocks (256ch @32x32): R13 config ----
    for (int i = 0; i < 2; ++i) {
        const half_t* in_h = (i == 0) ? x_h : cur_h;
        mfma_conv<3, 0, 1, 32, 2, 8, 4><<<dim3(64, 8), 256, 0, stream>>>(
            in_h, nullptr, 256, 0, wres + (size_t)(i * 2) * 589824, res_b + (i * 2) * 256,
            scrf, zpage, 256, 256, 32, 32, 0, 2);
        inorm_p1<float, 4><<<dim3(512), 256, 0, stream>>>(scrf, part, 256, 1024, 128);
        inorm_stats<<<dim3(4), 256, 0, stream>>>(part, stats, 256, 1024, 128);
        inorm_p2<float, 4><<<dim3(1024), 256, 0, stream>>>(scrf, tB_h, nullptr, nullptr,
                                                           stats, 256, 1024, 4, 1);
        mfma_conv<3, 0, 1, 32, 2, 8, 4><<<dim3(64, 8), 256, 0, stream>>>(
            tB_h, nullptr, 256, 0, wres + (size_t)(i * 2 + 1) * 589824, res_b + (i * 2 + 1) * 256,
            scrf, zpage, 256, 256, 32, 32, 0, 2);
        inorm_p1<float, 4><<<dim3(512), 256, 0, stream>>>(scrf, part, 256, 1024, 128);
        inorm_stats<<<dim3(4), 256, 0, stream>>>(part, stats, 256, 1024, 128);
        inorm_p2<float, 4><<<dim3(1024), 256, 0, stream>>>(scrf, cur_h, cur_f,
                                                           (i == 0) ? x_f : cur_f,
                                                           stats, 256, 1024, 4, 0);
    }

    // ---- conv1: up2+refpad2+5x5 (256->128) @64x64: R13 config ----
    mfma_conv<5, 1, 1, 32, 2, 16, 2><<<dim3(128, 4), 256, 0, stream>>>(
        cur_h, nullptr, 256, 0, w1t, b1, out1h, zpage, 128, 128, 64, 64, 0, 0);
    inorm_p1<half_t, 8><<<dim3(512), 256, 0, stream>>>(out1h, part, 128, 4096, 128);
    inorm_stats<<<dim3(4), 256, 0, stream>>>(part, stats, 128, 4096, 128);
    inorm_p2<half_t, 8><<<dim3(1024), 256, 0, stream>>>(out1h, out1h, nullptr, nullptr,
                                                        stats, 128, 4096, 4, 1);

    // ---- om2 = 3x3 zero-pad conv on concat[out1, s2c] -> 27ch fp32 NCHW: R13 ----
    mfma_conv<3, 0, 0, 32, 2, 8, 4><<<dim3(256, 1), 256, 0, stream>>>(
        out1h, s2c, 128, 128, off2t, off2_b, om2f, zpage, 27, 32, 64, 64, 0, 1);

    // ---- pre2 = deform_conv(skip2, om2): one block per tile, all 128 oc ----
    mfma_dcn<128, 1><<<dim3(256), 256, 0, stream>>>(s2c, om2f, dcn2t, dcn2_b, pre2h, 64, 64);

    // ---- conv2: WM=1 NM=4 (0.25 LDS reads/MFMA) with MINW=2 (128-VGPR budget) ----
    mfma_conv<5, 1, 1, 64, 1, 8, 2><<<dim3(1024, 1), 256, 0, stream>>>(
        pre2h, out1h, 128, 128, w2t, b2, out2h, zpage, 64, 64, 128, 128, 0, 0);
    inorm_p1<half_t, 8><<<dim3(1024), 256, 0, stream>>>(out2h, part, 64, 16384, 256);
    inorm_stats<<<dim3(4), 256, 0, stream>>>(part, stats, 64, 16384, 256);
    inorm_p2<half_t, 8><<<dim3(2048), 256, 0, stream>>>(out2h, out2h, nullptr, nullptr,
                                                        stats, 64, 16384, 4, 1);

    // ---- om1 = 3x3 zero-pad conv on concat[out2, s1c] -> 27ch fp32 NCHW: R13 ----
    mfma_conv<3, 0, 0, 32, 2, 8, 4><<<dim3(1024, 1), 256, 0, stream>>>(
        out2h, s1c, 64, 64, off1t, off1_b, om1f, zpage, 27, 32, 128, 128, 0, 1);

    // ---- pre1 = deform_conv(skip1, om1): one block per tile, all 64 oc ----
    mfma_dcn<64, 2><<<dim3(1024), 256, 0, stream>>>(s1c, om1f, dcn1t, dcn1_b, pre1h, 128, 128);

    // ---- final: 7x7 refpad3 concat[pre1,out2] -> 3ch fp32 NCHW + tanh ----
    mfma_conv<7, 0, 1, 16, 1, 8, 4><<<dim3(1024, 1), 256, 0, stream>>>(
        pre1h, out2h, 64, 64, w3t, b3, outp, zpage, 3, 16, 128, 128, 1, 1);

    // ---- offset_sum ----
    abs_sum_kernel<<<dim3(256), 256, 0, stream>>>(om1f, 4, 27, 16384, acc + 0);
    abs_sum_kernel<<<dim3(256), 256, 0, stream>>>(om2f, 4, 27, 4096, acc + 1);
    finalize_kernel<<<dim3(1), dim3(1), 0, stream>>>(acc, outp + 196608);
}

// Round 16
// 680.396 us; speedup vs baseline: 2.7397x; 1.5515x over previous
//
#include <hip/hip_runtime.h>
#include <cmath>

#define EPS 1e-5f

typedef _Float16 half_t;
typedef __attribute__((ext_vector_type(8))) _Float16 half8;
typedef __attribute__((ext_vector_type(8))) short short8;
typedef __attribute__((ext_vector_type(4))) float f32x4;
typedef __attribute__((ext_vector_type(2))) unsigned int uint2v;

__device__ __forceinline__ int reflect_idx(int p, int S) {
    if (p < 0) p = -p;
    if (p >= S) p = 2 * S - 2 - p;
    return p;
}
__device__ __forceinline__ float hlo(unsigned v) {
    return (float)__builtin_bit_cast(half_t, (unsigned short)(v & 0xffffu));
}
__device__ __forceinline__ float hhi(unsigned v) {
    return (float)__builtin_bit_cast(half_t, (unsigned short)(v >> 16));
}
__device__ __forceinline__ unsigned short hbits(float f) {
    return __builtin_bit_cast(unsigned short, (half_t)f);
}

// async global->LDS DMA, 16B per lane; lds dest = wave-uniform base + lane*16
__device__ __forceinline__ void gl_lds16(const half_t* g, char* l) {
    __builtin_amdgcn_global_load_lds(
        (const __attribute__((address_space(1))) unsigned int*)g,
        (__attribute__((address_space(3))) unsigned int*)l, 16, 0, 0);
}

// ---------------- weight transforms (fp32 -> fp16) ----------------
// conv weights [Co][Cin][KK] -> [cb][kk][Cop][32] where c = cb*32 + cl.
__global__ void wtrans_conv(const float* __restrict__ w, half_t* __restrict__ wt,
                            int Co, int Cop, int Cin, int KK)
{
    int i = blockIdx.x * 256 + threadIdx.x;
    int total = KK * Cop * Cin;
    if (i >= total) return;
    int cl = i & 31;
    int oc = (i >> 5) % Cop;
    int rest = (i >> 5) / Cop;     // cb*KK + kk
    int kk = rest % KK;
    int cb = rest / KK;
    int c = (cb << 5) + cl;
    float v = (oc < Co) ? w[((size_t)oc * Cin + c) * KK + kk] : 0.f;
    wt[i] = (half_t)v;
}

// dcn weights [Co][Cin][9] -> [cb][Co][32] with kidx = k*Cin + c = cb*32 + cl
__global__ void wtrans_dcn(const float* __restrict__ w, half_t* __restrict__ wt,
                           int Co, int Cin)
{
    int i = blockIdx.x * 256 + threadIdx.x;
    int total = Co * 9 * Cin;
    if (i >= total) return;
    int cl = i & 31;
    int oc = (i >> 5) % Co;
    int cb = (i >> 5) / Co;
    int kidx = (cb << 5) + cl;
    int k = kidx / Cin, c = kidx % Cin;
    wt[i] = (half_t)w[((size_t)oc * Cin + c) * 9 + k];
}

// ---------------- NCHW fp32 -> NHWC fp16 via LDS tile transpose ----------------
// Tile = 32 channels x 64 positions. Coalesced reads (64 consec floats/wave-half)
// and contiguous NHWC writes. Grid = B * (C/32) * (HW/64).
template<int WITH_F32>
__global__ void cvt_nchw_nhwc_t(const float* __restrict__ in, half_t* __restrict__ out,
                                float* __restrict__ outf, int C, int HW)
{
    __shared__ float tile[32][65];
    const int nct = C >> 5, npt = HW >> 6;
    const int blk = blockIdx.x;
    const int pt = blk % npt;
    const int ct = (blk / npt) % nct;
    const int b  = blk / (npt * nct);
    const int p0 = pt * 64, c0 = ct * 32;
    const int tid = threadIdx.x;

    const int pos = tid & 63, cs = tid >> 6;   // cs in 0..3
#pragma unroll
    for (int pass = 0; pass < 8; ++pass) {
        int c = cs + pass * 4;
        tile[c][pos] = in[((size_t)(b * C + c0 + c)) * HW + p0 + pos];
    }
    __syncthreads();
    const int cw = tid & 31, pw = tid >> 5;    // pw in 0..7
#pragma unroll
    for (int pass = 0; pass < 8; ++pass) {
        int p = pw + pass * 8;
        float v = tile[cw][p];
        size_t oidx = ((size_t)b * HW + p0 + p) * C + c0 + cw;
        out[oidx] = (half_t)v;
        if (WITH_F32) outf[oidx] = v;
    }
}

// ---------------- MFMA implicit-GEMM conv ----------------
// TH=8 x TW positions x COB ocs per block, 4 waves arranged WM x (4/WM).
// Wave register-blocks NM oc-tiles x NNW pos-tiles (R13-proven configs only).
// outfmt: 0 = fp16 NHWC (stride Co), 1 = fp32 NCHW (guarded), 2 = fp32 NHWC.
template<int K, int UP, int REFLECT, int COB, int WM, int TW, int MINW>
__global__ __launch_bounds__(256, MINW)
void mfma_conv(const half_t* __restrict__ in1, const half_t* __restrict__ in2,
               int C1, int C2,
               const half_t* __restrict__ wt, const float* __restrict__ bias,
               void* __restrict__ outp, const float* __restrict__ zp,
               int Co, int Cop, int Hout, int Wout, int act, int outfmt)
{
    constexpr int TH = 8, PAD = K / 2;
    constexpr int PR = TH + K - 1, PW = TW + K - 1;
    constexpr int NPOS = PR * PW, KK = K * K;
    constexpr int OUT_POS = TH * TW;
    constexpr int NT  = OUT_POS / 16;      // n-tiles total
    constexpr int MT  = COB / 16;          // m-tiles total
    constexpr int WN  = 4 / WM;
    constexpr int NM  = MT / WM;           // m-tiles per wave
    constexpr int NNW = NT / WN;           // n-tiles per wave
    constexpr int LDSB = NPOS * 64;
    constexpr int NELEM = NPOS * 4;
    constexpr int NE = (NELEM + 255) / 256;
    constexpr int EPI = OUT_POS * COB * 4; // epilogue tile worst case (fp32)
    constexpr int LDS_SZ = (2 * LDSB > EPI) ? 2 * LDSB : EPI;

    __shared__ __align__(16) char lds[LDS_SZ];

    const int Cin = C1 + C2;
    const int Hin = UP ? (Hout >> 1) : Hout;
    const int Win = UP ? (Wout >> 1) : Wout;
    const int NTX = Wout / TW, NTY = Hout / TH;

    const int tid = threadIdx.x;
    const int wv = tid >> 6, lane = tid & 63, l15 = lane & 15, kg = lane >> 4;
    const int bx = blockIdx.x;
    const int xt = (bx % NTX) * TW;
    const int yt = ((bx / NTX) % NTY) * TH;
    const int b  = bx / (NTX * NTY);
    const int ocb = blockIdx.y * COB;
    const int wm = wv % WM;
    const int wn = wv / WM;

    f32x4 acc[NM][NNW];
#pragma unroll
    for (int i = 0; i < NM; ++i)
#pragma unroll
        for (int t = 0; t < NNW; ++t) acc[i][t] = (f32x4){0.f, 0.f, 0.f, 0.f};

    int ipos[NNW];
#pragma unroll
    for (int t = 0; t < NNW; ++t) {
        int pos = (wn * NNW + t) * 16 + l15;
        ipos[t] = (pos / TW) * PW + (pos % TW);
    }

    // per-lane source offsets for each DMA issue (pre-swizzled channel group)
    unsigned offA[NE], offB[NE], okbits = 0;
#pragma unroll
    for (int i = 0; i < NE; ++i) {
        int e = tid + i * 256;
        if (e < NELEM) {
            int p = e >> 2;
            int g = (e & 3) ^ ((p >> 1) & 3);   // swizzled source group
            int py = p / PW, px = p % PW;
            int ly = yt + py - PAD, lx = xt + px - PAD;
            bool ok = true;
            if (REFLECT) { ly = reflect_idx(ly, Hout); lx = reflect_idx(lx, Wout); }
            else {
                ok = (ly >= 0) && (ly < Hout) && (lx >= 0) && (lx < Wout);
                if (!ok) { ly = 0; lx = 0; }
            }
            int sy = UP ? (ly >> 1) : ly;
            int sx = UP ? (lx >> 1) : lx;
            int esi = (b * Hin + sy) * Win + sx;
            offA[i] = (unsigned)(esi * C1 + g * 8);
            offB[i] = (unsigned)(esi * C2 + g * 8);
            if (ok) okbits |= (1u << i);
        }
    }

    auto issue = [&](int cb, int buf) {
        const bool inA = (cb * 32) < C1;
        const half_t* srcb = inA ? in1 + (size_t)(cb * 32)
                                 : in2 + (size_t)(cb * 32 - C1);
#pragma unroll
        for (int i = 0; i < NE; ++i) {
            const int e0 = i * 256 + wv * 64;      // wave-uniform slot base
            if (e0 < NELEM) {
                char* lb = lds + buf * LDSB + e0 * 16;
                const int e = e0 + lane;
                if (e < NELEM) {
                    unsigned off = inA ? offA[i] : offB[i];
                    const half_t* g = ((okbits >> i) & 1) ? srcb + off
                                                          : (const half_t*)zp;
                    gl_lds16(g, lb);
                }
            }
        }
    };

    const int NCB = Cin >> 5;
    const half_t* wb[NM];
#pragma unroll
    for (int i = 0; i < NM; ++i)
        wb[i] = wt + (size_t)(ocb + (wm * NM + i) * 16 + l15) * 32 + (kg << 3);

    issue(0, 0);
    int cur = 0;
    for (int cb = 0; cb < NCB; ++cb) {
        __syncthreads();                    // drains DMA -> buf[cur] ready
        if (cb + 1 < NCB) issue(cb + 1, cur ^ 1);   // next chunk in flight
        const size_t cbase = (size_t)cb * KK * Cop * 32;
        const char* lb = lds + cur * LDSB;

        // ---- software-pipelined kk loop: load kk+1 before MFMAs of kk ----
        half8 a_c[NM], b_c[NNW];
#pragma unroll
        for (int i = 0; i < NM; ++i)
            a_c[i] = *(const half8*)(wb[i] + cbase);
#pragma unroll
        for (int t = 0; t < NNW; ++t) {
            int idx = ipos[t];
            b_c[t] = *(const half8*)(lb + idx * 64 + ((kg ^ ((idx >> 1) & 3)) << 4));
        }
#pragma unroll
        for (int kk = 0; kk < KK; ++kk) {
            half8 a_n[NM], b_n[NNW];
            if (kk + 1 < KK) {
#pragma unroll
                for (int i = 0; i < NM; ++i)
                    a_n[i] = *(const half8*)(wb[i] + cbase + (size_t)(kk + 1) * Cop * 32);
                int ikk = ((kk + 1) / K) * PW + ((kk + 1) % K);
#pragma unroll
                for (int t = 0; t < NNW; ++t) {
                    int idx = ipos[t] + ikk;
                    b_n[t] = *(const half8*)(lb + idx * 64 + ((kg ^ ((idx >> 1) & 3)) << 4));
                }
            }
#pragma unroll
            for (int i = 0; i < NM; ++i)
#pragma unroll
                for (int t = 0; t < NNW; ++t)
                    acc[i][t] = __builtin_amdgcn_mfma_f32_16x16x32_f16(a_c[i], b_c[t], acc[i][t], 0, 0, 0);
            if (kk + 1 < KK) {
#pragma unroll
                for (int i = 0; i < NM; ++i) a_c[i] = a_n[i];
#pragma unroll
                for (int t = 0; t < NNW; ++t) b_c[t] = b_n[t];
            }
        }
        cur ^= 1;
    }

    // ---- epilogue ----
    if (outfmt == 1) {
        // direct fp32 NCHW store with oc guard (om convs + final conv)
#pragma unroll
        for (int i = 0; i < NM; ++i)
#pragma unroll
            for (int t = 0; t < NNW; ++t) {
                int pos = (wn * NNW + t) * 16 + l15;
                int y = yt + pos / TW, x = xt + pos % TW;
#pragma unroll
                for (int j = 0; j < 4; ++j) {
                    int oc = ocb + (wm * NM + i) * 16 + kg * 4 + j;
                    if (oc < Co) {
                        float v = acc[i][t][j] + bias[oc];
                        if (act) v = tanhf(v);
                        ((float*)outp)[(((size_t)b * Co + oc) * Hout + y) * Wout + x] = v;
                    }
                }
            }
    } else if (outfmt == 0) {
        // fp16 NHWC via LDS-staged coalesced store
        __syncthreads();
        half_t* tile = (half_t*)lds;       // OUT_POS x COB fp16
#pragma unroll
        for (int i = 0; i < NM; ++i) {
            float bv[4];
#pragma unroll
            for (int j = 0; j < 4; ++j) bv[j] = bias[ocb + (wm * NM + i) * 16 + kg * 4 + j];
#pragma unroll
            for (int t = 0; t < NNW; ++t) {
                int pos = (wn * NNW + t) * 16 + l15;
#pragma unroll
                for (int j = 0; j < 4; ++j)
                    tile[pos * COB + (wm * NM + i) * 16 + kg * 4 + j] = (half_t)(acc[i][t][j] + bv[j]);
            }
        }
        __syncthreads();
        for (int e = tid; e < OUT_POS * COB / 8; e += 256) {
            int pos = e / (COB / 8), ch = (e % (COB / 8)) * 8;
            int y = yt + pos / TW, xx = xt + pos % TW;
            short8 v = *(const short8*)(tile + pos * COB + ch);
            *(short8*)((half_t*)outp + ((size_t)(b * Hout + y) * Wout + xx) * Co + ocb + ch) = v;
        }
    } else {
        // fp32 NHWC via LDS-staged coalesced store
        __syncthreads();
        float* tile = (float*)lds;         // OUT_POS x COB fp32
#pragma unroll
        for (int i = 0; i < NM; ++i) {
            float bv[4];
#pragma unroll
            for (int j = 0; j < 4; ++j) bv[j] = bias[ocb + (wm * NM + i) * 16 + kg * 4 + j];
#pragma unroll
            for (int t = 0; t < NNW; ++t) {
                int pos = (wn * NNW + t) * 16 + l15;
#pragma unroll
                for (int j = 0; j < 4; ++j)
                    tile[pos * COB + (wm * NM + i) * 16 + kg * 4 + j] = acc[i][t][j] + bv[j];
            }
        }
        __syncthreads();
        for (int e = tid; e < OUT_POS * COB / 4; e += 256) {
            int pos = e / (COB / 4), ch = (e % (COB / 4)) * 4;
            int y = yt + pos / TW, xx = xt + pos % TW;
            f32x4 v = *(const f32x4*)(tile + pos * COB + ch);
            *(f32x4*)((float*)outp + ((size_t)(b * Hout + y) * Wout + xx) * Co + ocb + ch) = v;
        }
    }
}

// ---------------- MFMA deformable conv (one block = ALL Co for its tile) ----------------
template<int C, int MINW>
__global__ __launch_bounds__(256, MINW)
void mfma_dcn(const half_t* __restrict__ xs, const float* __restrict__ om,
              const half_t* __restrict__ wtd, const float* __restrict__ bias,
              half_t* __restrict__ outb, int H, int W)
{
    constexpr int NCK = C / 32;            // 32-ch chunks
    constexpr int NQ  = C / 4;             // channel quads
    constexpr int MT  = C / 16;            // m-tiles (Co == C)
    constexpr int NM  = MT / 4;            // m-tiles per wave
    constexpr int ITERS = 64 * NQ / 256;   // gather iters per thread per tap
    __shared__ __align__(16) char lds[NCK * 4096];
    __shared__ int   addrL[64][4];
    __shared__ float wgtL[64][4];

    const int NTX = W / 8, NTY = H / 8;
    const int tid = threadIdx.x;
    const int wv = tid >> 6, lane = tid & 63, l15 = lane & 15, kg = lane >> 4;
    const int bx = blockIdx.x;
    const int xt = (bx % NTX) * 8;
    const int yt = ((bx / NTX) % NTY) * 8;
    const int b  = bx / (NTX * NTY);
    const int HW = H * W;

    f32x4 acc[NM][4];
#pragma unroll
    for (int i = 0; i < NM; ++i)
#pragma unroll
        for (int t = 0; t < 4; ++t) acc[i][t] = (f32x4){0.f, 0.f, 0.f, 0.f};

    int boff[4];
#pragma unroll
    for (int t = 0; t < 4; ++t)
        boff[t] = (t * 16 + l15) * 64 + ((kg ^ (l15 & 3)) << 4);

    for (int k = 0; k < 9; ++k) {
        __syncthreads();               // prev MFMA reads of lds done
        if (tid < 64) {
            int pos = tid;
            int y = yt + (pos >> 3), x = xt + (pos & 7);
            size_t obase = (size_t)b * 27 * HW + (size_t)y * W + x;
            float offy = om[obase + (size_t)(2 * k) * HW];
            float offx = om[obase + (size_t)(2 * k + 1) * HW];
            float ml   = om[obase + (size_t)(18 + k) * HW];
            float mk = 1.f / (1.f + expf(-ml));
            float py = (float)(y - 1 + k / 3) + offy;
            float px = (float)(x - 1 + k % 3) + offx;
            float fy = floorf(py), fx = floorf(px);
            int y0 = (int)fy, x0 = (int)fx;
            float dy = py - fy, dx = px - fx;
            int y1 = y0 + 1, x1 = x0 + 1;
            bool vy0 = (y0 >= 0) && (y0 < H), vy1 = (y1 >= 0) && (y1 < H);
            bool vx0 = (x0 >= 0) && (x0 < W), vx1 = (x1 >= 0) && (x1 < W);
            wgtL[pos][0] = (vy0 && vx0) ? (1.f - dy) * (1.f - dx) * mk : 0.f;
            wgtL[pos][1] = (vy0 && vx1) ? (1.f - dy) * dx * mk : 0.f;
            wgtL[pos][2] = (vy1 && vx0) ? dy * (1.f - dx) * mk : 0.f;
            wgtL[pos][3] = (vy1 && vx1) ? dy * dx * mk : 0.f;
            int yc0 = min(max(y0, 0), H - 1), yc1 = min(max(y1, 0), H - 1);
            int xc0 = min(max(x0, 0), W - 1), xc1 = min(max(x1, 0), W - 1);
            addrL[pos][0] = ((b * H + yc0) * W + xc0) * C;
            addrL[pos][1] = ((b * H + yc0) * W + xc1) * C;
            addrL[pos][2] = ((b * H + yc1) * W + xc0) * C;
            addrL[pos][3] = ((b * H + yc1) * W + xc1) * C;
        }
        __syncthreads();               // tables ready
#pragma unroll
        for (int it = 0; it < ITERS; ++it) {
            int u = tid + it * 256;
            int pos = u / NQ;
            int cq = u % NQ;
            int c = cq * 4;
            float w00 = wgtL[pos][0], w01 = wgtL[pos][1];
            float w10 = wgtL[pos][2], w11 = wgtL[pos][3];
            const half_t* base = xs + c;
            uint2v q00 = *(const uint2v*)(base + addrL[pos][0]);
            uint2v q01 = *(const uint2v*)(base + addrL[pos][1]);
            uint2v q10 = *(const uint2v*)(base + addrL[pos][2]);
            uint2v q11 = *(const uint2v*)(base + addrL[pos][3]);
            float f0 = hlo(q00[0]) * w00 + hlo(q01[0]) * w01 + hlo(q10[0]) * w10 + hlo(q11[0]) * w11;
            float f1 = hhi(q00[0]) * w00 + hhi(q01[0]) * w01 + hhi(q10[0]) * w10 + hhi(q11[0]) * w11;
            float f2 = hlo(q00[1]) * w00 + hlo(q01[1]) * w01 + hlo(q10[1]) * w10 + hlo(q11[1]) * w11;
            float f3 = hhi(q00[1]) * w00 + hhi(q01[1]) * w01 + hhi(q10[1]) * w10 + hhi(q11[1]) * w11;
            uint2v r;
            r[0] = (unsigned)hbits(f0) | ((unsigned)hbits(f1) << 16);
            r[1] = (unsigned)hbits(f2) | ((unsigned)hbits(f3) << 16);
            int chunk = c >> 5, cpl = (c & 31) >> 1;
            *(uint2v*)(lds + chunk * 4096 + pos * 64 +
                       ((((cpl >> 2) ^ (pos & 3)) << 4) | ((cpl & 3) << 2))) = r;
        }
        __syncthreads();               // gathered chunk ready
#pragma unroll
        for (int cbl = 0; cbl < NCK; ++cbl) {
            int cb = k * NCK + cbl;
            half8 a[NM];
#pragma unroll
            for (int i = 0; i < NM; ++i)
                a[i] = *(const half8*)(wtd + ((size_t)cb * C + (wv * NM + i) * 16 + l15) * 32 + (kg << 3));
            half8 bf[4];
#pragma unroll
            for (int t = 0; t < 4; ++t)
                bf[t] = *(const half8*)(lds + cbl * 4096 + boff[t]);
#pragma unroll
            for (int i = 0; i < NM; ++i)
#pragma unroll
                for (int t = 0; t < 4; ++t)
                    acc[i][t] = __builtin_amdgcn_mfma_f32_16x16x32_f16(a[i], bf[t], acc[i][t], 0, 0, 0);
        }
    }

    // ---- LDS-staged coalesced epilogue (64 pos x C fp16 fits in chunk lds) ----
    float bv[NM][4];
#pragma unroll
    for (int i = 0; i < NM; ++i)
#pragma unroll
        for (int j = 0; j < 4; ++j) bv[i][j] = bias[(wv * NM + i) * 16 + kg * 4 + j];
    __syncthreads();
    half_t* tile = (half_t*)lds;
#pragma unroll
    for (int i = 0; i < NM; ++i)
#pragma unroll
        for (int t = 0; t < 4; ++t) {
            int pos = t * 16 + l15;
#pragma unroll
            for (int j = 0; j < 4; ++j)
                tile[pos * C + (wv * NM + i) * 16 + kg * 4 + j] = (half_t)(acc[i][t][j] + bv[i][j]);
        }
    __syncthreads();
    for (int e = tid; e < 64 * C / 8; e += 256) {
        int pos = e / (C / 8), ch = (e % (C / 8)) * 8;
        int y = yt + (pos >> 3), xx = xt + (pos & 7);
        short8 v = *(const short8*)(tile + pos * C + ch);
        *(short8*)(outb + ((size_t)(b * H + y) * W + xx) * C + ch) = v;
    }
}

// ---------------- InstanceNorm (NHWC), 3 kernels, vectorized ----------------
template<typename TI, int V>
__global__ void inorm_p1(const TI* __restrict__ in, float* __restrict__ part,
                         int Cc, int HW, int NS)
{
    const int CG = Cc / V, G = 256 / CG;
    const int bs = blockIdx.x, s = bs % NS, b = bs / NS;
    const int tid = threadIdx.x;
    const int cg = tid % CG, r = tid / CG;
    const int rows = HW / NS, p0 = s * rows;
    const TI* bp = in + (size_t)b * HW * Cc + (size_t)cg * V;

    float sm[V], sq[V];
#pragma unroll
    for (int j = 0; j < V; ++j) { sm[j] = 0.f; sq[j] = 0.f; }
    for (int p = p0 + r; p < p0 + rows; p += G) {
        const TI* a = bp + (size_t)p * Cc;
        if constexpr (sizeof(TI) == 2) {
            half8 hv = *(const half8*)a;
#pragma unroll
            for (int j = 0; j < V; ++j) { float v = (float)hv[j]; sm[j] += v; sq[j] += v * v; }
        } else {
            f32x4 fv = *(const f32x4*)a;
#pragma unroll
            for (int j = 0; j < V; ++j) { float v = fv[j]; sm[j] += v; sq[j] += v * v; }
        }
    }
    __shared__ float red[256 * 2 * V];
    float* my = red + tid * 2 * V;
#pragma unroll
    for (int j = 0; j < V; ++j) { my[j] = sm[j]; my[V + j] = sq[j]; }
    __syncthreads();
    for (int step = G >> 1; step > 0; step >>= 1) {
        if (r < step) {
            const float* ot = red + ((r + step) * CG + cg) * 2 * V;
#pragma unroll
            for (int j = 0; j < V; ++j) { my[j] += ot[j]; my[V + j] += ot[V + j]; }
        }
        __syncthreads();
    }
    if (r == 0) {
        float* pp = part + ((size_t)(b * NS + s) * Cc + cg * V) * 2;
#pragma unroll
        for (int j = 0; j < V; ++j) { pp[2 * j] = my[j]; pp[2 * j + 1] = my[V + j]; }
    }
}

__global__ void inorm_stats(const float* __restrict__ part, float* __restrict__ stats,
                            int Cc, int HW, int NS)
{
    int b = blockIdx.x;
    for (int c = threadIdx.x; c < Cc; c += 256) {
        float S = 0.f, Q = 0.f;
        for (int s = 0; s < NS; ++s) {
            const float* pp = part + ((size_t)(b * NS + s) * Cc + c) * 2;
            S += pp[0]; Q += pp[1];
        }
        float m = S / HW;
        float var = Q / HW - m * m;
        if (var < 0.f) var = 0.f;
        stats[(b * Cc + c) * 2]     = m;
        stats[(b * Cc + c) * 2 + 1] = rsqrtf(var + EPS);
    }
}

template<typename TI, int V>
__global__ void inorm_p2(const TI* __restrict__ in, half_t* __restrict__ out_h,
                         float* __restrict__ out_f, const float* __restrict__ resid,
                         const float* __restrict__ stats,
                         int Cc, int HW, int B, int relu)
{
    int nvec = B * HW * Cc / V;
    for (int i = blockIdx.x * 256 + threadIdx.x; i < nvec; i += gridDim.x * 256) {
        size_t E = (size_t)i * V;
        int c = (int)(E % Cc);
        int b = (int)(E / ((size_t)Cc * HW));
        float vv[V];
        if constexpr (sizeof(TI) == 2) {
            half8 hv = *(const half8*)(in + E);
#pragma unroll
            for (int j = 0; j < V; ++j) vv[j] = (float)hv[j];
        } else {
            f32x4 fv = *(const f32x4*)(in + E);
#pragma unroll
            for (int j = 0; j < V; ++j) vv[j] = fv[j];
        }
        const float* st = stats + ((size_t)b * Cc + c) * 2;
#pragma unroll
        for (int j = 0; j < V; ++j) {
            float v = (vv[j] - st[2 * j]) * st[2 * j + 1];
            if (relu) v = fmaxf(v, 0.f);
            vv[j] = v;
        }
        if (resid) {
#pragma unroll
            for (int j = 0; j < V; j += 4) {
                f32x4 rv = *(const f32x4*)(resid + E + j);
                vv[j] += rv[0]; vv[j + 1] += rv[1]; vv[j + 2] += rv[2]; vv[j + 3] += rv[3];
            }
        }
        if (out_h) {
            half8 ov = (half8)0;
#pragma unroll
            for (int j = 0; j < V; ++j) ov[j] = (half_t)vv[j];
            if constexpr (sizeof(TI) == 2) {
                *(half8*)(out_h + E) = ov;
            } else {
                for (int j = 0; j < V; ++j) out_h[E + j] = (half_t)vv[j];
            }
        }
        if (out_f) {
#pragma unroll
            for (int j = 0; j < V; j += 4) {
                f32x4 ov = { vv[j], vv[j + 1], vv[j + 2], vv[j + 3] };
                *(f32x4*)(out_f + E + j) = ov;
            }
        }
    }
}

// ---------------- offset |.| mean ----------------
__global__ void abs_sum_kernel(const float* __restrict__ om, int B, int Ctot, int HW,
                               float* __restrict__ acc)
{
    long long total = (long long)B * 18 * HW;
    float s = 0.f;
    for (long long i = (long long)blockIdx.x * blockDim.x + threadIdx.x; i < total;
         i += (long long)gridDim.x * blockDim.x) {
        int pos = (int)(i % HW);
        int c   = (int)((i / HW) % 18);
        int b   = (int)(i / ((long long)18 * HW));
        s += fabsf(om[((size_t)(b * Ctot + c)) * HW + pos]);
    }
#pragma unroll
    for (int off = 32; off > 0; off >>= 1) s += __shfl_down(s, off);
    __shared__ float ws_[4];
    int lane = threadIdx.x & 63, w = threadIdx.x >> 6;
    if (lane == 0) ws_[w] = s;
    __syncthreads();
    if (threadIdx.x == 0) {
        float t = 0.f;
        int nw = blockDim.x >> 6;
        for (int i = 0; i < nw; ++i) t += ws_[i];
        atomicAdd(acc, t);
    }
}

__global__ void zero_kernel(float* p, int n) {
    int i = blockIdx.x * 256 + threadIdx.x;
    if (i < n) p[i] = 0.f;
}

__global__ void finalize_kernel(const float* __restrict__ acc, float* __restrict__ out) {
    out[0] = 0.5f * (acc[0] / (4.f * 18.f * 128.f * 128.f)
                   + acc[1] / (4.f * 18.f * 64.f * 64.f));
}

extern "C" void kernel_launch(void* const* d_in, const int* in_sizes, int n_in,
                              void* d_out, int out_size, void* d_ws, size_t ws_size,
                              hipStream_t stream)
{
    const float* x      = (const float*)d_in[0];
    const float* skip1  = (const float*)d_in[1];
    const float* skip2  = (const float*)d_in[2];
    const float* res_w  = (const float*)d_in[3];
    const float* res_b  = (const float*)d_in[4];
    const float* w1     = (const float*)d_in[5];
    const float* b1     = (const float*)d_in[6];
    const float* w2     = (const float*)d_in[7];
    const float* b2     = (const float*)d_in[8];
    const float* w3     = (const float*)d_in[9];
    const float* b3     = (const float*)d_in[10];
    const float* off2_w = (const float*)d_in[11];
    const float* off2_b = (const float*)d_in[12];
    const float* dcn2_w = (const float*)d_in[13];
    const float* dcn2_b = (const float*)d_in[14];
    const float* off1_w = (const float*)d_in[15];
    const float* off1_b = (const float*)d_in[16];
    const float* dcn1_w = (const float*)d_in[17];
    const float* dcn1_b = (const float*)d_in[18];

    char* base = (char*)d_ws;
    size_t o = 0;
    auto alloc = [&](size_t bytes) { size_t r = o; o += (bytes + 15) & ~(size_t)15; return r; };
    half_t* x_h   = (half_t*)(base + alloc(1048576ull * 2));
    float*  x_f   = (float*)(base + alloc(1048576ull * 4));
    half_t* s1c   = (half_t*)(base + alloc(4194304ull * 2));
    half_t* s2c   = (half_t*)(base + alloc(2097152ull * 2));
    float*  scrf  = (float*)(base + alloc(1048576ull * 4));
    half_t* tB_h  = (half_t*)(base + alloc(1048576ull * 2));
    float*  cur_f = (float*)(base + alloc(1048576ull * 4));
    half_t* cur_h = (half_t*)(base + alloc(1048576ull * 2));
    half_t* out1h = (half_t*)(base + alloc(2097152ull * 2));
    half_t* pre2h = (half_t*)(base + alloc(2097152ull * 2));
    half_t* out2h = (half_t*)(base + alloc(4194304ull * 2));
    half_t* pre1h = (half_t*)(base + alloc(4194304ull * 2));
    float*  om2f  = (float*)(base + alloc(442368ull * 4));
    float*  om1f  = (float*)(base + alloc(1769472ull * 4));
    half_t* wres  = (half_t*)(base + alloc(4ull * 589824 * 2));
    half_t* w1t   = (half_t*)(base + alloc(819200ull * 2));
    half_t* w2t   = (half_t*)(base + alloc(409600ull * 2));
    half_t* off2t = (half_t*)(base + alloc(73728ull * 2));
    half_t* off1t = (half_t*)(base + alloc(36864ull * 2));
    half_t* w3t   = (half_t*)(base + alloc(100352ull * 2));
    half_t* dcn2t = (half_t*)(base + alloc(147456ull * 2));
    half_t* dcn1t = (half_t*)(base + alloc(36864ull * 2));
    float*  part  = (float*)(base + alloc(262144ull * 4));
    float*  stats = (float*)(base + alloc(2048ull * 4));
    float*  zpage = (float*)(base + alloc(4096));       // zero page for OOB DMA
    float*  acc   = (float*)(base + alloc(16));
    if (ws_size < o) return;

    float* outp = (float*)d_out;

    zero_kernel<<<dim3(5), 256, 0, stream>>>(zpage, 1026);

    // ---- converts (LDS tile-transposed, coalesced) ----
    cvt_nchw_nhwc_t<1><<<dim3(512), 256, 0, stream>>>(x, x_h, x_f, 256, 1024);
    cvt_nchw_nhwc_t<0><<<dim3(2048), 256, 0, stream>>>(skip1, s1c, nullptr, 64, 16384);
    cvt_nchw_nhwc_t<0><<<dim3(1024), 256, 0, stream>>>(skip2, s2c, nullptr, 128, 4096);

    // ---- weight transforms ----
    for (int j = 0; j < 4; ++j)
        wtrans_conv<<<dim3(2304), 256, 0, stream>>>(res_w + (size_t)j * 589824,
                                                    wres + (size_t)j * 589824, 256, 256, 256, 9);
    wtrans_conv<<<dim3(3200), 256, 0, stream>>>(w1, w1t, 128, 128, 256, 25);
    wtrans_conv<<<dim3(1600), 256, 0, stream>>>(w2, w2t, 64, 64, 256, 25);
    wtrans_conv<<<dim3(288), 256, 0, stream>>>(off2_w, off2t, 27, 32, 256, 9);
    wtrans_conv<<<dim3(144), 256, 0, stream>>>(off1_w, off1t, 27, 32, 128, 9);
    wtrans_conv<<<dim3(392), 256, 0, stream>>>(w3, w3t, 3, 16, 128, 49);
    wtrans_dcn<<<dim3(576), 256, 0, stream>>>(dcn2_w, dcn2t, 128, 128);
    wtrans_dcn<<<dim3(144), 256, 0, stream>>>(dcn1_w, dcn1t, 64, 64);

    // ---- residual blocks (256ch @32x32): R13 config ----
    for (int i = 0; i < 2; ++i) {
        const half_t* in_h = (i == 0) ? x_h : cur_h;
        mfma_conv<3, 0, 1, 32, 2, 8, 4><<<dim3(64, 8), 256, 0, stream>>>(
            in_h, nullptr, 256, 0, wres + (size_t)(i * 2) * 589824, res_b + (i * 2) * 256,
            scrf, zpage, 256, 256, 32, 32, 0, 2);
        inorm_p1<float, 4><<<dim3(512), 256, 0, stream>>>(scrf, part, 256, 1024, 128);
        inorm_stats<<<dim3(4), 256, 0, stream>>>(part, stats, 256, 1024, 128);
        inorm_p2<float, 4><<<dim3(1024), 256, 0, stream>>>(scrf, tB_h, nullptr, nullptr,
                                                           stats, 256, 1024, 4, 1);
        mfma_conv<3, 0, 1, 32, 2, 8, 4><<<dim3(64, 8), 256, 0, stream>>>(
            tB_h, nullptr, 256, 0, wres + (size_t)(i * 2 + 1) * 589824, res_b + (i * 2 + 1) * 256,
            scrf, zpage, 256, 256, 32, 32, 0, 2);
        inorm_p1<float, 4><<<dim3(512), 256, 0, stream>>>(scrf, part, 256, 1024, 128);
        inorm_stats<<<dim3(4), 256, 0, stream>>>(part, stats, 256, 1024, 128);
        inorm_p2<float, 4><<<dim3(1024), 256, 0, stream>>>(scrf, cur_h, cur_f,
                                                           (i == 0) ? x_f : cur_f,
                                                           stats, 256, 1024, 4, 0);
    }

    // ---- conv1: up2+refpad2+5x5 (256->128) @64x64: R13 config ----
    mfma_conv<5, 1, 1, 32, 2, 16, 2><<<dim3(128, 4), 256, 0, stream>>>(
        cur_h, nullptr, 256, 0, w1t, b1, out1h, zpage, 128, 128, 64, 64, 0, 0);
    inorm_p1<half_t, 8><<<dim3(512), 256, 0, stream>>>(out1h, part, 128, 4096, 128);
    inorm_stats<<<dim3(4), 256, 0, stream>>>(part, stats, 128, 4096, 128);
    inorm_p2<half_t, 8><<<dim3(1024), 256, 0, stream>>>(out1h, out1h, nullptr, nullptr,
                                                        stats, 128, 4096, 4, 1);

    // ---- om2 = 3x3 zero-pad conv on concat[out1, s2c] -> 27ch fp32 NCHW: R13 ----
    mfma_conv<3, 0, 0, 32, 2, 8, 4><<<dim3(256, 1), 256, 0, stream>>>(
        out1h, s2c, 128, 128, off2t, off2_b, om2f, zpage, 27, 32, 64, 64, 0, 1);

    // ---- pre2 = deform_conv(skip2, om2): one block per tile, all 128 oc ----
    mfma_dcn<128, 1><<<dim3(256), 256, 0, stream>>>(s2c, om2f, dcn2t, dcn2_b, pre2h, 64, 64);

    // ---- conv2: R13 config <5,1,1,64,2,16,2> (512 blocks) ----
    mfma_conv<5, 1, 1, 64, 2, 16, 2><<<dim3(512, 1), 256, 0, stream>>>(
        pre2h, out1h, 128, 128, w2t, b2, out2h, zpage, 64, 64, 128, 128, 0, 0);
    inorm_p1<half_t, 8><<<dim3(1024), 256, 0, stream>>>(out2h, part, 64, 16384, 256);
    inorm_stats<<<dim3(4), 256, 0, stream>>>(part, stats, 64, 16384, 256);
    inorm_p2<half_t, 8><<<dim3(2048), 256, 0, stream>>>(out2h, out2h, nullptr, nullptr,
                                                        stats, 64, 16384, 4, 1);

    // ---- om1 = 3x3 zero-pad conv on concat[out2, s1c] -> 27ch fp32 NCHW: R13 ----
    mfma_conv<3, 0, 0, 32, 2, 8, 4><<<dim3(1024, 1), 256, 0, stream>>>(
        out2h, s1c, 64, 64, off1t, off1_b, om1f, zpage, 27, 32, 128, 128, 0, 1);

    // ---- pre1 = deform_conv(skip1, om1): one block per tile, all 64 oc ----
    mfma_dcn<64, 2><<<dim3(1024), 256, 0, stream>>>(s1c, om1f, dcn1t, dcn1_b, pre1h, 128, 128);

    // ---- final: 7x7 refpad3 concat[pre1,out2] -> 3ch fp32 NCHW + tanh ----
    mfma_conv<7, 0, 1, 16, 1, 8, 4><<<dim3(1024, 1), 256, 0, stream>>>(
        pre1h, out2h, 64, 64, w3t, b3, outp, zpage, 3, 16, 128, 128, 1, 1);

    // ---- offset_sum ----
    abs_sum_kernel<<<dim3(256), 256, 0, stream>>>(om1f, 4, 27, 16384, acc + 0);
    abs_sum_kernel<<<dim3(256), 256, 0, stream>>>(om2f, 4, 27, 4096, acc + 1);
    finalize_kernel<<<dim3(1), dim3(1), 0, stream>>>(acc, outp + 196608);
}

// Round 17
// 492.447 us; speedup vs baseline: 3.7853x; 1.3817x over previous
//
#include <hip/hip_runtime.h>
#include <cmath>

#define EPS 1e-5f

typedef _Float16 half_t;
typedef __attribute__((ext_vector_type(8))) _Float16 half8;
typedef __attribute__((ext_vector_type(8))) short short8;
typedef __attribute__((ext_vector_type(4))) float f32x4;
typedef __attribute__((ext_vector_type(2))) unsigned int uint2v;

__device__ __forceinline__ int reflect_idx(int p, int S) {
    if (p < 0) p = -p;
    if (p >= S) p = 2 * S - 2 - p;
    return p;
}
__device__ __forceinline__ float hlo(unsigned v) {
    return (float)__builtin_bit_cast(half_t, (unsigned short)(v & 0xffffu));
}
__device__ __forceinline__ float hhi(unsigned v) {
    return (float)__builtin_bit_cast(half_t, (unsigned short)(v >> 16));
}
__device__ __forceinline__ unsigned short hbits(float f) {
    return __builtin_bit_cast(unsigned short, (half_t)f);
}

// async global->LDS DMA, 16B per lane; lds dest = wave-uniform base + lane*16
__device__ __forceinline__ void gl_lds16(const half_t* g, char* l) {
    __builtin_amdgcn_global_load_lds(
        (const __attribute__((address_space(1))) unsigned int*)g,
        (__attribute__((address_space(3))) unsigned int*)l, 16, 0, 0);
}

// ---------------- weight transforms (fp32 -> fp16) ----------------
// conv weights [Co][Cin][KK] -> [cb][kk][Cop][32] where c = cb*32 + cl.
__global__ void wtrans_conv(const float* __restrict__ w, half_t* __restrict__ wt,
                            int Co, int Cop, int Cin, int KK)
{
    int i = blockIdx.x * 256 + threadIdx.x;
    int total = KK * Cop * Cin;
    if (i >= total) return;
    int cl = i & 31;
    int oc = (i >> 5) % Cop;
    int rest = (i >> 5) / Cop;     // cb*KK + kk
    int kk = rest % KK;
    int cb = rest / KK;
    int c = (cb << 5) + cl;
    float v = (oc < Co) ? w[((size_t)oc * Cin + c) * KK + kk] : 0.f;
    wt[i] = (half_t)v;
}

// dcn weights [Co][Cin][9] -> [cb][Co][32] with kidx = k*Cin + c = cb*32 + cl
__global__ void wtrans_dcn(const float* __restrict__ w, half_t* __restrict__ wt,
                           int Co, int Cin)
{
    int i = blockIdx.x * 256 + threadIdx.x;
    int total = Co * 9 * Cin;
    if (i >= total) return;
    int cl = i & 31;
    int oc = (i >> 5) % Co;
    int cb = (i >> 5) / Co;
    int kidx = (cb << 5) + cl;
    int k = kidx / Cin, c = kidx % Cin;
    wt[i] = (half_t)w[((size_t)oc * Cin + c) * 9 + k];
}

// ---------------- NCHW fp32 -> NHWC fp16 via LDS tile transpose ----------------
template<int WITH_F32>
__global__ void cvt_nchw_nhwc_t(const float* __restrict__ in, half_t* __restrict__ out,
                                float* __restrict__ outf, int C, int HW)
{
    __shared__ float tile[32][65];
    const int nct = C >> 5, npt = HW >> 6;
    const int blk = blockIdx.x;
    const int pt = blk % npt;
    const int ct = (blk / npt) % nct;
    const int b  = blk / (npt * nct);
    const int p0 = pt * 64, c0 = ct * 32;
    const int tid = threadIdx.x;

    const int pos = tid & 63, cs = tid >> 6;   // cs in 0..3
#pragma unroll
    for (int pass = 0; pass < 8; ++pass) {
        int c = cs + pass * 4;
        tile[c][pos] = in[((size_t)(b * C + c0 + c)) * HW + p0 + pos];
    }
    __syncthreads();
    const int cw = tid & 31, pw = tid >> 5;    // pw in 0..7
#pragma unroll
    for (int pass = 0; pass < 8; ++pass) {
        int p = pw + pass * 8;
        float v = tile[cw][p];
        size_t oidx = ((size_t)b * HW + p0 + p) * C + c0 + cw;
        out[oidx] = (half_t)v;
        if (WITH_F32) outf[oidx] = v;
    }
}

// ---------------- MFMA implicit-GEMM conv ----------------
// TH=8 x TW positions x COB ocs per block, 4 waves arranged WM x (4/WM).
// Fused epilogue extras: `part` (per-tile per-channel sum/sumsq for IN) on the
// NHWC paths; `absacc` (sum |v| over oc<18) on the fp32 NCHW path.
// outfmt: 0 = fp16 NHWC (stride Co), 1 = fp32 NCHW (guarded), 2 = fp32 NHWC.
template<int K, int UP, int REFLECT, int COB, int WM, int TW, int MINW>
__global__ __launch_bounds__(256, MINW)
void mfma_conv(const half_t* __restrict__ in1, const half_t* __restrict__ in2,
               int C1, int C2,
               const half_t* __restrict__ wt, const float* __restrict__ bias,
               void* __restrict__ outp, const float* __restrict__ zp,
               int Co, int Cop, int Hout, int Wout, int act, int outfmt,
               float* __restrict__ part, float* __restrict__ absacc)
{
    constexpr int TH = 8, PAD = K / 2;
    constexpr int PR = TH + K - 1, PW = TW + K - 1;
    constexpr int NPOS = PR * PW, KK = K * K;
    constexpr int OUT_POS = TH * TW;
    constexpr int NT  = OUT_POS / 16;      // n-tiles total
    constexpr int MT  = COB / 16;          // m-tiles total
    constexpr int WN  = 4 / WM;
    constexpr int NM  = MT / WM;           // m-tiles per wave
    constexpr int NNW = NT / WN;           // n-tiles per wave
    constexpr int LDSB = NPOS * 64;
    constexpr int NELEM = NPOS * 4;
    constexpr int NE = (NELEM + 255) / 256;
    constexpr int EPI = OUT_POS * COB * 4; // epilogue tile worst case (fp32)
    constexpr int LDS_SZ = (2 * LDSB > EPI) ? 2 * LDSB : EPI;

    __shared__ __align__(16) char lds[LDS_SZ + 2048];  // +2KB reduce scratch

    const int Cin = C1 + C2;
    const int Hin = UP ? (Hout >> 1) : Hout;
    const int Win = UP ? (Wout >> 1) : Wout;
    const int NTX = Wout / TW, NTY = Hout / TH;

    const int tid = threadIdx.x;
    const int wv = tid >> 6, lane = tid & 63, l15 = lane & 15, kg = lane >> 4;
    const int bx = blockIdx.x;
    const int xt = (bx % NTX) * TW;
    const int yt = ((bx / NTX) % NTY) * TH;
    const int b  = bx / (NTX * NTY);
    const int ocb = blockIdx.y * COB;
    const int wm = wv % WM;
    const int wn = wv / WM;

    f32x4 acc[NM][NNW];
#pragma unroll
    for (int i = 0; i < NM; ++i)
#pragma unroll
        for (int t = 0; t < NNW; ++t) acc[i][t] = (f32x4){0.f, 0.f, 0.f, 0.f};

    int ipos[NNW];
#pragma unroll
    for (int t = 0; t < NNW; ++t) {
        int pos = (wn * NNW + t) * 16 + l15;
        ipos[t] = (pos / TW) * PW + (pos % TW);
    }

    // per-lane source offsets for each DMA issue (pre-swizzled channel group)
    unsigned offA[NE], offB[NE], okbits = 0;
#pragma unroll
    for (int i = 0; i < NE; ++i) {
        int e = tid + i * 256;
        if (e < NELEM) {
            int p = e >> 2;
            int g = (e & 3) ^ ((p >> 1) & 3);   // swizzled source group
            int py = p / PW, px = p % PW;
            int ly = yt + py - PAD, lx = xt + px - PAD;
            bool ok = true;
            if (REFLECT) { ly = reflect_idx(ly, Hout); lx = reflect_idx(lx, Wout); }
            else {
                ok = (ly >= 0) && (ly < Hout) && (lx >= 0) && (lx < Wout);
                if (!ok) { ly = 0; lx = 0; }
            }
            int sy = UP ? (ly >> 1) : ly;
            int sx = UP ? (lx >> 1) : lx;
            int esi = (b * Hin + sy) * Win + sx;
            offA[i] = (unsigned)(esi * C1 + g * 8);
            offB[i] = (unsigned)(esi * C2 + g * 8);
            if (ok) okbits |= (1u << i);
        }
    }

    auto issue = [&](int cb, int buf) {
        const bool inA = (cb * 32) < C1;
        const half_t* srcb = inA ? in1 + (size_t)(cb * 32)
                                 : in2 + (size_t)(cb * 32 - C1);
#pragma unroll
        for (int i = 0; i < NE; ++i) {
            const int e0 = i * 256 + wv * 64;      // wave-uniform slot base
            if (e0 < NELEM) {
                char* lb = lds + buf * LDSB + e0 * 16;
                const int e = e0 + lane;
                if (e < NELEM) {
                    unsigned off = inA ? offA[i] : offB[i];
                    const half_t* g = ((okbits >> i) & 1) ? srcb + off
                                                          : (const half_t*)zp;
                    gl_lds16(g, lb);
                }
            }
        }
    };

    const int NCB = Cin >> 5;
    const half_t* wb[NM];
#pragma unroll
    for (int i = 0; i < NM; ++i)
        wb[i] = wt + (size_t)(ocb + (wm * NM + i) * 16 + l15) * 32 + (kg << 3);

    issue(0, 0);
    int cur = 0;
    for (int cb = 0; cb < NCB; ++cb) {
        __syncthreads();                    // drains DMA -> buf[cur] ready
        if (cb + 1 < NCB) issue(cb + 1, cur ^ 1);   // next chunk in flight
        const size_t cbase = (size_t)cb * KK * Cop * 32;
        const char* lb = lds + cur * LDSB;

        // ---- software-pipelined kk loop: load kk+1 before MFMAs of kk ----
        half8 a_c[NM], b_c[NNW];
#pragma unroll
        for (int i = 0; i < NM; ++i)
            a_c[i] = *(const half8*)(wb[i] + cbase);
#pragma unroll
        for (int t = 0; t < NNW; ++t) {
            int idx = ipos[t];
            b_c[t] = *(const half8*)(lb + idx * 64 + ((kg ^ ((idx >> 1) & 3)) << 4));
        }
#pragma unroll
        for (int kk = 0; kk < KK; ++kk) {
            half8 a_n[NM], b_n[NNW];
            if (kk + 1 < KK) {
#pragma unroll
                for (int i = 0; i < NM; ++i)
                    a_n[i] = *(const half8*)(wb[i] + cbase + (size_t)(kk + 1) * Cop * 32);
                int ikk = ((kk + 1) / K) * PW + ((kk + 1) % K);
#pragma unroll
                for (int t = 0; t < NNW; ++t) {
                    int idx = ipos[t] + ikk;
                    b_n[t] = *(const half8*)(lb + idx * 64 + ((kg ^ ((idx >> 1) & 3)) << 4));
                }
            }
#pragma unroll
            for (int i = 0; i < NM; ++i)
#pragma unroll
                for (int t = 0; t < NNW; ++t)
                    acc[i][t] = __builtin_amdgcn_mfma_f32_16x16x32_f16(a_c[i], b_c[t], acc[i][t], 0, 0, 0);
            if (kk + 1 < KK) {
#pragma unroll
                for (int i = 0; i < NM; ++i) a_c[i] = a_n[i];
#pragma unroll
                for (int t = 0; t < NNW; ++t) b_c[t] = b_n[t];
            }
        }
        cur ^= 1;
    }

    // ---- epilogue ----
    if (outfmt == 1) {
        // direct fp32 NCHW store with oc guard (om convs + final conv)
        float asum = 0.f;
#pragma unroll
        for (int i = 0; i < NM; ++i)
#pragma unroll
            for (int t = 0; t < NNW; ++t) {
                int pos = (wn * NNW + t) * 16 + l15;
                int y = yt + pos / TW, x = xt + pos % TW;
#pragma unroll
                for (int j = 0; j < 4; ++j) {
                    int oc = ocb + (wm * NM + i) * 16 + kg * 4 + j;
                    if (oc < Co) {
                        float v = acc[i][t][j] + bias[oc];
                        if (act) v = tanhf(v);
                        ((float*)outp)[(((size_t)b * Co + oc) * Hout + y) * Wout + x] = v;
                        if (absacc && oc < 18) asum += fabsf(v);
                    }
                }
            }
        if (absacc) {
            float* red = (float*)(lds + LDS_SZ);
            red[tid] = asum;
            __syncthreads();
            for (int st = 128; st > 0; st >>= 1) {
                if (tid < st) red[tid] += red[tid + st];
                __syncthreads();
            }
            if (tid == 0) atomicAdd(absacc, red[0]);
        }
    } else if (outfmt == 0) {
        // fp16 NHWC via LDS-staged coalesced store (+ fused inorm partial sums)
        __syncthreads();
        half_t* tile = (half_t*)lds;       // OUT_POS x COB fp16
#pragma unroll
        for (int i = 0; i < NM; ++i) {
            float bv[4];
#pragma unroll
            for (int j = 0; j < 4; ++j) bv[j] = bias[ocb + (wm * NM + i) * 16 + kg * 4 + j];
#pragma unroll
            for (int t = 0; t < NNW; ++t) {
                int pos = (wn * NNW + t) * 16 + l15;
#pragma unroll
                for (int j = 0; j < 4; ++j)
                    tile[pos * COB + (wm * NM + i) * 16 + kg * 4 + j] = (half_t)(acc[i][t][j] + bv[j]);
            }
        }
        __syncthreads();
        for (int e = tid; e < OUT_POS * COB / 8; e += 256) {
            int pos = e / (COB / 8), ch = (e % (COB / 8)) * 8;
            int y = yt + pos / TW, xx = xt + pos % TW;
            short8 v = *(const short8*)(tile + pos * COB + ch);
            *(short8*)((half_t*)outp + ((size_t)(b * Hout + y) * Wout + xx) * Co + ocb + ch) = v;
        }
        if (part) {
            float* red = (float*)(lds + LDS_SZ);
            constexpr int G2 = 256 / COB;
            int c = tid % COB, r = tid / COB;
            float sm = 0.f, sq = 0.f;
            for (int p = r; p < OUT_POS; p += G2) {
                float v = (float)tile[p * COB + c];
                sm += v; sq += v * v;
            }
            red[tid * 2] = sm; red[tid * 2 + 1] = sq;
            __syncthreads();
            if (r == 0) {
                for (int g = 1; g < G2; ++g) {
                    sm += red[(g * COB + c) * 2];
                    sq += red[(g * COB + c) * 2 + 1];
                }
                int s = bx % (NTX * NTY);
                float* pp = part + ((size_t)(b * NTX * NTY + s) * Co + ocb + c) * 2;
                pp[0] = sm; pp[1] = sq;
            }
        }
    } else {
        // fp32 NHWC via LDS-staged coalesced store (+ fused inorm partial sums)
        __syncthreads();
        float* tile = (float*)lds;         // OUT_POS x COB fp32
#pragma unroll
        for (int i = 0; i < NM; ++i) {
            float bv[4];
#pragma unroll
            for (int j = 0; j < 4; ++j) bv[j] = bias[ocb + (wm * NM + i) * 16 + kg * 4 + j];
#pragma unroll
            for (int t = 0; t < NNW; ++t) {
                int pos = (wn * NNW + t) * 16 + l15;
#pragma unroll
                for (int j = 0; j < 4; ++j)
                    tile[pos * COB + (wm * NM + i) * 16 + kg * 4 + j] = acc[i][t][j] + bv[j];
            }
        }
        __syncthreads();
        for (int e = tid; e < OUT_POS * COB / 4; e += 256) {
            int pos = e / (COB / 4), ch = (e % (COB / 4)) * 4;
            int y = yt + pos / TW, xx = xt + pos % TW;
            f32x4 v = *(const f32x4*)(tile + pos * COB + ch);
            *(f32x4*)((float*)outp + ((size_t)(b * Hout + y) * Wout + xx) * Co + ocb + ch) = v;
        }
        if (part) {
            float* red = (float*)(lds + LDS_SZ);
            constexpr int G2 = 256 / COB;
            int c = tid % COB, r = tid / COB;
            float sm = 0.f, sq = 0.f;
            for (int p = r; p < OUT_POS; p += G2) {
                float v = tile[p * COB + c];
                sm += v; sq += v * v;
            }
            red[tid * 2] = sm; red[tid * 2 + 1] = sq;
            __syncthreads();
            if (r == 0) {
                for (int g = 1; g < G2; ++g) {
                    sm += red[(g * COB + c) * 2];
                    sq += red[(g * COB + c) * 2 + 1];
                }
                int s = bx % (NTX * NTY);
                float* pp = part + ((size_t)(b * NTX * NTY + s) * Co + ocb + c) * 2;
                pp[0] = sm; pp[1] = sq;
            }
        }
    }
}

// ---------------- MFMA deformable conv (one block = ALL Co for its tile) ----------------
template<int C, int MINW>
__global__ __launch_bounds__(256, MINW)
void mfma_dcn(const half_t* __restrict__ xs, const float* __restrict__ om,
              const half_t* __restrict__ wtd, const float* __restrict__ bias,
              half_t* __restrict__ outb, int H, int W)
{
    constexpr int NCK = C / 32;            // 32-ch chunks
    constexpr int NQ  = C / 4;             // channel quads
    constexpr int MT  = C / 16;            // m-tiles (Co == C)
    constexpr int NM  = MT / 4;            // m-tiles per wave
    constexpr int ITERS = 64 * NQ / 256;   // gather iters per thread per tap
    __shared__ __align__(16) char lds[NCK * 4096];
    __shared__ int   addrL[64][4];
    __shared__ float wgtL[64][4];

    const int NTX = W / 8, NTY = H / 8;
    const int tid = threadIdx.x;
    const int wv = tid >> 6, lane = tid & 63, l15 = lane & 15, kg = lane >> 4;
    const int bx = blockIdx.x;
    const int xt = (bx % NTX) * 8;
    const int yt = ((bx / NTX) % NTY) * 8;
    const int b  = bx / (NTX * NTY);
    const int HW = H * W;

    f32x4 acc[NM][4];
#pragma unroll
    for (int i = 0; i < NM; ++i)
#pragma unroll
        for (int t = 0; t < 4; ++t) acc[i][t] = (f32x4){0.f, 0.f, 0.f, 0.f};

    int boff[4];
#pragma unroll
    for (int t = 0; t < 4; ++t)
        boff[t] = (t * 16 + l15) * 64 + ((kg ^ (l15 & 3)) << 4);

    for (int k = 0; k < 9; ++k) {
        __syncthreads();               // prev MFMA reads of lds done
        if (tid < 64) {
            int pos = tid;
            int y = yt + (pos >> 3), x = xt + (pos & 7);
            size_t obase = (size_t)b * 27 * HW + (size_t)y * W + x;
            float offy = om[obase + (size_t)(2 * k) * HW];
            float offx = om[obase + (size_t)(2 * k + 1) * HW];
            float ml   = om[obase + (size_t)(18 + k) * HW];
            float mk = 1.f / (1.f + expf(-ml));
            float py = (float)(y - 1 + k / 3) + offy;
            float px = (float)(x - 1 + k % 3) + offx;
            float fy = floorf(py), fx = floorf(px);
            int y0 = (int)fy, x0 = (int)fx;
            float dy = py - fy, dx = px - fx;
            int y1 = y0 + 1, x1 = x0 + 1;
            bool vy0 = (y0 >= 0) && (y0 < H), vy1 = (y1 >= 0) && (y1 < H);
            bool vx0 = (x0 >= 0) && (x0 < W), vx1 = (x1 >= 0) && (x1 < W);
            wgtL[pos][0] = (vy0 && vx0) ? (1.f - dy) * (1.f - dx) * mk : 0.f;
            wgtL[pos][1] = (vy0 && vx1) ? (1.f - dy) * dx * mk : 0.f;
            wgtL[pos][2] = (vy1 && vx0) ? dy * (1.f - dx) * mk : 0.f;
            wgtL[pos][3] = (vy1 && vx1) ? dy * dx * mk : 0.f;
            int yc0 = min(max(y0, 0), H - 1), yc1 = min(max(y1, 0), H - 1);
            int xc0 = min(max(x0, 0), W - 1), xc1 = min(max(x1, 0), W - 1);
            addrL[pos][0] = ((b * H + yc0) * W + xc0) * C;
            addrL[pos][1] = ((b * H + yc0) * W + xc1) * C;
            addrL[pos][2] = ((b * H + yc1) * W + xc0) * C;
            addrL[pos][3] = ((b * H + yc1) * W + xc1) * C;
        }
        __syncthreads();               // tables ready
#pragma unroll
        for (int it = 0; it < ITERS; ++it) {
            int u = tid + it * 256;
            int pos = u / NQ;
            int cq = u % NQ;
            int c = cq * 4;
            float w00 = wgtL[pos][0], w01 = wgtL[pos][1];
            float w10 = wgtL[pos][2], w11 = wgtL[pos][3];
            const half_t* base = xs + c;
            uint2v q00 = *(const uint2v*)(base + addrL[pos][0]);
            uint2v q01 = *(const uint2v*)(base + addrL[pos][1]);
            uint2v q10 = *(const uint2v*)(base + addrL[pos][2]);
            uint2v q11 = *(const uint2v*)(base + addrL[pos][3]);
            float f0 = hlo(q00[0]) * w00 + hlo(q01[0]) * w01 + hlo(q10[0]) * w10 + hlo(q11[0]) * w11;
            float f1 = hhi(q00[0]) * w00 + hhi(q01[0]) * w01 + hhi(q10[0]) * w10 + hhi(q11[0]) * w11;
            float f2 = hlo(q00[1]) * w00 + hlo(q01[1]) * w01 + hlo(q10[1]) * w10 + hlo(q11[1]) * w11;
            float f3 = hhi(q00[1]) * w00 + hhi(q01[1]) * w01 + hhi(q10[1]) * w10 + hhi(q11[1]) * w11;
            uint2v r;
            r[0] = (unsigned)hbits(f0) | ((unsigned)hbits(f1) << 16);
            r[1] = (unsigned)hbits(f2) | ((unsigned)hbits(f3) << 16);
            int chunk = c >> 5, cpl = (c & 31) >> 1;
            *(uint2v*)(lds + chunk * 4096 + pos * 64 +
                       ((((cpl >> 2) ^ (pos & 3)) << 4) | ((cpl & 3) << 2))) = r;
        }
        __syncthreads();               // gathered chunk ready
#pragma unroll
        for (int cbl = 0; cbl < NCK; ++cbl) {
            int cb = k * NCK + cbl;
            half8 a[NM];
#pragma unroll
            for (int i = 0; i < NM; ++i)
                a[i] = *(const half8*)(wtd + ((size_t)cb * C + (wv * NM + i) * 16 + l15) * 32 + (kg << 3));
            half8 bf[4];
#pragma unroll
            for (int t = 0; t < 4; ++t)
                bf[t] = *(const half8*)(lds + cbl * 4096 + boff[t]);
#pragma unroll
            for (int i = 0; i < NM; ++i)
#pragma unroll
                for (int t = 0; t < 4; ++t)
                    acc[i][t] = __builtin_amdgcn_mfma_f32_16x16x32_f16(a[i], bf[t], acc[i][t], 0, 0, 0);
        }
    }

    // ---- LDS-staged coalesced epilogue (64 pos x C fp16 fits in chunk lds) ----
    float bv[NM][4];
#pragma unroll
    for (int i = 0; i < NM; ++i)
#pragma unroll
        for (int j = 0; j < 4; ++j) bv[i][j] = bias[(wv * NM + i) * 16 + kg * 4 + j];
    __syncthreads();
    half_t* tile = (half_t*)lds;
#pragma unroll
    for (int i = 0; i < NM; ++i)
#pragma unroll
        for (int t = 0; t < 4; ++t) {
            int pos = t * 16 + l15;
#pragma unroll
            for (int j = 0; j < 4; ++j)
                tile[pos * C + (wv * NM + i) * 16 + kg * 4 + j] = (half_t)(acc[i][t][j] + bv[i][j]);
        }
    __syncthreads();
    for (int e = tid; e < 64 * C / 8; e += 256) {
        int pos = e / (C / 8), ch = (e % (C / 8)) * 8;
        int y = yt + (pos >> 3), xx = xt + (pos & 7);
        short8 v = *(const short8*)(tile + pos * C + ch);
        *(short8*)(outb + ((size_t)(b * H + y) * W + xx) * C + ch) = v;
    }
}

// ---------------- InstanceNorm: stats reduce + normalize (p1 fused into convs) ----------------
__global__ void inorm_stats(const float* __restrict__ part, float* __restrict__ stats,
                            int Cc, int HW, int NS)
{
    int b = blockIdx.x;
    for (int c = threadIdx.x; c < Cc; c += 256) {
        float S = 0.f, Q = 0.f;
        for (int s = 0; s < NS; ++s) {
            const float* pp = part + ((size_t)(b * NS + s) * Cc + c) * 2;
            S += pp[0]; Q += pp[1];
        }
        float m = S / HW;
        float var = Q / HW - m * m;
        if (var < 0.f) var = 0.f;
        stats[(b * Cc + c) * 2]     = m;
        stats[(b * Cc + c) * 2 + 1] = rsqrtf(var + EPS);
    }
}

template<typename TI, int V>
__global__ void inorm_p2(const TI* __restrict__ in, half_t* __restrict__ out_h,
                         float* __restrict__ out_f, const float* __restrict__ resid,
                         const float* __restrict__ stats,
                         int Cc, int HW, int B, int relu)
{
    int nvec = B * HW * Cc / V;
    for (int i = blockIdx.x * 256 + threadIdx.x; i < nvec; i += gridDim.x * 256) {
        size_t E = (size_t)i * V;
        int c = (int)(E % Cc);
        int b = (int)(E / ((size_t)Cc * HW));
        float vv[V];
        if constexpr (sizeof(TI) == 2) {
            half8 hv = *(const half8*)(in + E);
#pragma unroll
            for (int j = 0; j < V; ++j) vv[j] = (float)hv[j];
        } else {
            f32x4 fv = *(const f32x4*)(in + E);
#pragma unroll
            for (int j = 0; j < V; ++j) vv[j] = fv[j];
        }
        const float* st = stats + ((size_t)b * Cc + c) * 2;
#pragma unroll
        for (int j = 0; j < V; ++j) {
            float v = (vv[j] - st[2 * j]) * st[2 * j + 1];
            if (relu) v = fmaxf(v, 0.f);
            vv[j] = v;
        }
        if (resid) {
#pragma unroll
            for (int j = 0; j < V; j += 4) {
                f32x4 rv = *(const f32x4*)(resid + E + j);
                vv[j] += rv[0]; vv[j + 1] += rv[1]; vv[j + 2] += rv[2]; vv[j + 3] += rv[3];
            }
        }
        if (out_h) {
            half8 ov = (half8)0;
#pragma unroll
            for (int j = 0; j < V; ++j) ov[j] = (half_t)vv[j];
            if constexpr (sizeof(TI) == 2) {
                *(half8*)(out_h + E) = ov;
            } else {
                for (int j = 0; j < V; ++j) out_h[E + j] = (half_t)vv[j];
            }
        }
        if (out_f) {
#pragma unroll
            for (int j = 0; j < V; j += 4) {
                f32x4 ov = { vv[j], vv[j + 1], vv[j + 2], vv[j + 3] };
                *(f32x4*)(out_f + E + j) = ov;
            }
        }
    }
}

__global__ void zero_kernel(float* p, int n) {
    int i = blockIdx.x * 256 + threadIdx.x;
    if (i < n) p[i] = 0.f;
}

__global__ void finalize_kernel(const float* __restrict__ acc, float* __restrict__ out) {
    out[0] = 0.5f * (acc[0] / (4.f * 18.f * 128.f * 128.f)
                   + acc[1] / (4.f * 18.f * 64.f * 64.f));
}

extern "C" void kernel_launch(void* const* d_in, const int* in_sizes, int n_in,
                              void* d_out, int out_size, void* d_ws, size_t ws_size,
                              hipStream_t stream)
{
    const float* x      = (const float*)d_in[0];
    const float* skip1  = (const float*)d_in[1];
    const float* skip2  = (const float*)d_in[2];
    const float* res_w  = (const float*)d_in[3];
    const float* res_b  = (const float*)d_in[4];
    const float* w1     = (const float*)d_in[5];
    const float* b1     = (const float*)d_in[6];
    const float* w2     = (const float*)d_in[7];
    const float* b2     = (const float*)d_in[8];
    const float* w3     = (const float*)d_in[9];
    const float* b3     = (const float*)d_in[10];
    const float* off2_w = (const float*)d_in[11];
    const float* off2_b = (const float*)d_in[12];
    const float* dcn2_w = (const float*)d_in[13];
    const float* dcn2_b = (const float*)d_in[14];
    const float* off1_w = (const float*)d_in[15];
    const float* off1_b = (const float*)d_in[16];
    const float* dcn1_w = (const float*)d_in[17];
    const float* dcn1_b = (const float*)d_in[18];

    char* base = (char*)d_ws;
    size_t o = 0;
    auto alloc = [&](size_t bytes) { size_t r = o; o += (bytes + 15) & ~(size_t)15; return r; };
    half_t* x_h   = (half_t*)(base + alloc(1048576ull * 2));
    float*  x_f   = (float*)(base + alloc(1048576ull * 4));
    half_t* s1c   = (half_t*)(base + alloc(4194304ull * 2));
    half_t* s2c   = (half_t*)(base + alloc(2097152ull * 2));
    float*  scrf  = (float*)(base + alloc(1048576ull * 4));
    half_t* tB_h  = (half_t*)(base + alloc(1048576ull * 2));
    float*  cur_f = (float*)(base + alloc(1048576ull * 4));
    half_t* cur_h = (half_t*)(base + alloc(1048576ull * 2));
    half_t* out1h = (half_t*)(base + alloc(2097152ull * 2));
    half_t* pre2h = (half_t*)(base + alloc(2097152ull * 2));
    half_t* out2h = (half_t*)(base + alloc(4194304ull * 2));
    half_t* pre1h = (half_t*)(base + alloc(4194304ull * 2));
    float*  om2f  = (float*)(base + alloc(442368ull * 4));
    float*  om1f  = (float*)(base + alloc(1769472ull * 4));
    half_t* wres  = (half_t*)(base + alloc(4ull * 589824 * 2));
    half_t* w1t   = (half_t*)(base + alloc(819200ull * 2));
    half_t* w2t   = (half_t*)(base + alloc(409600ull * 2));
    half_t* off2t = (half_t*)(base + alloc(73728ull * 2));
    half_t* off1t = (half_t*)(base + alloc(36864ull * 2));
    half_t* w3t   = (half_t*)(base + alloc(100352ull * 2));
    half_t* dcn2t = (half_t*)(base + alloc(147456ull * 2));
    half_t* dcn1t = (half_t*)(base + alloc(36864ull * 2));
    float*  part  = (float*)(base + alloc(262144ull * 4));
    float*  stats = (float*)(base + alloc(2048ull * 4));
    float*  zpage = (float*)(base + alloc(4096));       // zero page for OOB DMA
    float*  acc   = (float*)(base + alloc(16));
    if (ws_size < o) return;

    float* outp = (float*)d_out;

    zero_kernel<<<dim3(5), 256, 0, stream>>>(zpage, 1026);

    // ---- converts (LDS tile-transposed, coalesced) ----
    cvt_nchw_nhwc_t<1><<<dim3(512), 256, 0, stream>>>(x, x_h, x_f, 256, 1024);
    cvt_nchw_nhwc_t<0><<<dim3(2048), 256, 0, stream>>>(skip1, s1c, nullptr, 64, 16384);
    cvt_nchw_nhwc_t<0><<<dim3(1024), 256, 0, stream>>>(skip2, s2c, nullptr, 128, 4096);

    // ---- weight transforms ----
    for (int j = 0; j < 4; ++j)
        wtrans_conv<<<dim3(2304), 256, 0, stream>>>(res_w + (size_t)j * 589824,
                                                    wres + (size_t)j * 589824, 256, 256, 256, 9);
    wtrans_conv<<<dim3(3200), 256, 0, stream>>>(w1, w1t, 128, 128, 256, 25);
    wtrans_conv<<<dim3(1600), 256, 0, stream>>>(w2, w2t, 64, 64, 256, 25);
    wtrans_conv<<<dim3(288), 256, 0, stream>>>(off2_w, off2t, 27, 32, 256, 9);
    wtrans_conv<<<dim3(144), 256, 0, stream>>>(off1_w, off1t, 27, 32, 128, 9);
    wtrans_conv<<<dim3(392), 256, 0, stream>>>(w3, w3t, 3, 16, 128, 49);
    wtrans_dcn<<<dim3(576), 256, 0, stream>>>(dcn2_w, dcn2t, 128, 128);
    wtrans_dcn<<<dim3(144), 256, 0, stream>>>(dcn1_w, dcn1t, 64, 64);

    // ---- residual blocks (256ch @32x32): R13 config, fused p1 (NS=16 tiles) ----
    for (int i = 0; i < 2; ++i) {
        const half_t* in_h = (i == 0) ? x_h : cur_h;
        mfma_conv<3, 0, 1, 32, 2, 8, 4><<<dim3(64, 8), 256, 0, stream>>>(
            in_h, nullptr, 256, 0, wres + (size_t)(i * 2) * 589824, res_b + (i * 2) * 256,
            scrf, zpage, 256, 256, 32, 32, 0, 2, part, nullptr);
        inorm_stats<<<dim3(4), 256, 0, stream>>>(part, stats, 256, 1024, 16);
        inorm_p2<float, 4><<<dim3(1024), 256, 0, stream>>>(scrf, tB_h, nullptr, nullptr,
                                                           stats, 256, 1024, 4, 1);
        mfma_conv<3, 0, 1, 32, 2, 8, 4><<<dim3(64, 8), 256, 0, stream>>>(
            tB_h, nullptr, 256, 0, wres + (size_t)(i * 2 + 1) * 589824, res_b + (i * 2 + 1) * 256,
            scrf, zpage, 256, 256, 32, 32, 0, 2, part, nullptr);
        inorm_stats<<<dim3(4), 256, 0, stream>>>(part, stats, 256, 1024, 16);
        inorm_p2<float, 4><<<dim3(1024), 256, 0, stream>>>(scrf, cur_h, cur_f,
                                                           (i == 0) ? x_f : cur_f,
                                                           stats, 256, 1024, 4, 0);
    }

    // ---- conv1: up2+refpad2+5x5 (256->128) @64x64, fused p1 (NS=32 tiles) ----
    mfma_conv<5, 1, 1, 32, 2, 16, 2><<<dim3(128, 4), 256, 0, stream>>>(
        cur_h, nullptr, 256, 0, w1t, b1, out1h, zpage, 128, 128, 64, 64, 0, 0, part, nullptr);
    inorm_stats<<<dim3(4), 256, 0, stream>>>(part, stats, 128, 4096, 32);
    inorm_p2<half_t, 8><<<dim3(1024), 256, 0, stream>>>(out1h, out1h, nullptr, nullptr,
                                                        stats, 128, 4096, 4, 1);

    // ---- om2 = 3x3 zero-pad conv -> 27ch fp32 NCHW, fused |offset| (acc+1) ----
    mfma_conv<3, 0, 0, 32, 2, 8, 4><<<dim3(256, 1), 256, 0, stream>>>(
        out1h, s2c, 128, 128, off2t, off2_b, om2f, zpage, 27, 32, 64, 64, 0, 1,
        nullptr, acc + 1);

    // ---- pre2 = deform_conv(skip2, om2) ----
    mfma_dcn<128, 1><<<dim3(256), 256, 0, stream>>>(s2c, om2f, dcn2t, dcn2_b, pre2h, 64, 64);

    // ---- conv2: R13 config, fused p1 (NS=128 tiles) ----
    mfma_conv<5, 1, 1, 64, 2, 16, 2><<<dim3(512, 1), 256, 0, stream>>>(
        pre2h, out1h, 128, 128, w2t, b2, out2h, zpage, 64, 64, 128, 128, 0, 0, part, nullptr);
    inorm_stats<<<dim3(4), 256, 0, stream>>>(part, stats, 64, 16384, 128);
    inorm_p2<half_t, 8><<<dim3(2048), 256, 0, stream>>>(out2h, out2h, nullptr, nullptr,
                                                        stats, 64, 16384, 4, 1);

    // ---- om1 = 3x3 zero-pad conv -> 27ch fp32 NCHW, fused |offset| (acc+0) ----
    mfma_conv<3, 0, 0, 32, 2, 8, 4><<<dim3(1024, 1), 256, 0, stream>>>(
        out2h, s1c, 64, 64, off1t, off1_b, om1f, zpage, 27, 32, 128, 128, 0, 1,
        nullptr, acc + 0);

    // ---- pre1 = deform_conv(skip1, om1) ----
    mfma_dcn<64, 2><<<dim3(1024), 256, 0, stream>>>(s1c, om1f, dcn1t, dcn1_b, pre1h, 128, 128);

    // ---- final: 7x7 refpad3 concat[pre1,out2] -> 3ch fp32 NCHW + tanh ----
    mfma_conv<7, 0, 1, 16, 1, 8, 4><<<dim3(1024, 1), 256, 0, stream>>>(
        pre1h, out2h, 64, 64, w3t, b3, outp, zpage, 3, 16, 128, 128, 1, 1,
        nullptr, nullptr);

    // ---- offset_sum scalar ----
    finalize_kernel<<<dim3(1), dim3(1), 0, stream>>>(acc, outp + 196608);
}

// Round 18
// 472.781 us; speedup vs baseline: 3.9428x; 1.0416x over previous
//
#include <hip/hip_runtime.h>
#include <cmath>

#define EPS 1e-5f

typedef _Float16 half_t;
typedef __attribute__((ext_vector_type(8))) _Float16 half8;
typedef __attribute__((ext_vector_type(8))) short short8;
typedef __attribute__((ext_vector_type(4))) float f32x4;
typedef __attribute__((ext_vector_type(2))) unsigned int uint2v;

__device__ __forceinline__ int reflect_idx(int p, int S) {
    if (p < 0) p = -p;
    if (p >= S) p = 2 * S - 2 - p;
    return p;
}
__device__ __forceinline__ float hlo(unsigned v) {
    return (float)__builtin_bit_cast(half_t, (unsigned short)(v & 0xffffu));
}
__device__ __forceinline__ float hhi(unsigned v) {
    return (float)__builtin_bit_cast(half_t, (unsigned short)(v >> 16));
}
__device__ __forceinline__ unsigned short hbits(float f) {
    return __builtin_bit_cast(unsigned short, (half_t)f);
}

// async global->LDS DMA, 16B per lane; lds dest = wave-uniform base + lane*16
__device__ __forceinline__ void gl_lds16(const half_t* g, char* l) {
    __builtin_amdgcn_global_load_lds(
        (const __attribute__((address_space(1))) unsigned int*)g,
        (__attribute__((address_space(3))) unsigned int*)l, 16, 0, 0);
}

// ---------------- weight transforms (fp32 -> fp16) ----------------
// conv weights [Co][Cin][KK] -> [cb][kk][Cop][32] where c = cb*32 + cl.
__global__ void wtrans_conv(const float* __restrict__ w, half_t* __restrict__ wt,
                            int Co, int Cop, int Cin, int KK)
{
    int i = blockIdx.x * 256 + threadIdx.x;
    int total = KK * Cop * Cin;
    if (i >= total) return;
    int cl = i & 31;
    int oc = (i >> 5) % Cop;
    int rest = (i >> 5) / Cop;     // cb*KK + kk
    int kk = rest % KK;
    int cb = rest / KK;
    int c = (cb << 5) + cl;
    float v = (oc < Co) ? w[((size_t)oc * Cin + c) * KK + kk] : 0.f;
    wt[i] = (half_t)v;
}

// 4 res-block weight sets in one launch (j = which set)
__global__ void wtrans_res4(const float* __restrict__ w, half_t* __restrict__ wt)
{
    int i = blockIdx.x * 256 + threadIdx.x;
    const int per = 9 * 256 * 256;
    if (i >= 4 * per) return;
    int j = i / per, r = i % per;
    int cl = r & 31;
    int oc = (r >> 5) % 256;
    int rest = (r >> 5) / 256;     // cb*9 + kk
    int kk = rest % 9;
    int cb = rest / 9;
    int c = (cb << 5) + cl;
    wt[(size_t)j * per + r] =
        (half_t)w[(size_t)j * per + ((size_t)oc * 256 + c) * 9 + kk];
}

// dcn weights [Co][Cin][9] -> [cb][Co][32] with kidx = k*Cin + c = cb*32 + cl
__global__ void wtrans_dcn(const float* __restrict__ w, half_t* __restrict__ wt,
                           int Co, int Cin)
{
    int i = blockIdx.x * 256 + threadIdx.x;
    int total = Co * 9 * Cin;
    if (i >= total) return;
    int cl = i & 31;
    int oc = (i >> 5) % Co;
    int cb = (i >> 5) / Co;
    int kidx = (cb << 5) + cl;
    int k = kidx / Cin, c = kidx % Cin;
    wt[i] = (half_t)w[((size_t)oc * Cin + c) * 9 + k];
}

// ---------------- NCHW fp32 -> NHWC fp16, all 3 inputs in one launch ----------------
__global__ void cvt_all(const float* __restrict__ x, half_t* __restrict__ x_h,
                        float* __restrict__ x_f,
                        const float* __restrict__ s1, half_t* __restrict__ s1c,
                        const float* __restrict__ s2, half_t* __restrict__ s2c)
{
    __shared__ float tile[32][65];
    int blk = blockIdx.x;
    const float* in; half_t* out; float* outf = nullptr; int C, HW;
    if (blk < 512)       { in = x;  out = x_h; outf = x_f; C = 256; HW = 1024;  }
    else if (blk < 2560) { in = s1; out = s1c; C = 64;  HW = 16384; blk -= 512; }
    else                 { in = s2; out = s2c; C = 128; HW = 4096;  blk -= 2560; }
    const int nct = C >> 5, npt = HW >> 6;
    const int pt = blk % npt;
    const int ct = (blk / npt) % nct;
    const int b  = blk / (npt * nct);
    const int p0 = pt * 64, c0 = ct * 32;
    const int tid = threadIdx.x;

    const int pos = tid & 63, cs = tid >> 6;
#pragma unroll
    for (int pass = 0; pass < 8; ++pass) {
        int c = cs + pass * 4;
        tile[c][pos] = in[((size_t)(b * C + c0 + c)) * HW + p0 + pos];
    }
    __syncthreads();
    const int cw = tid & 31, pw = tid >> 5;
#pragma unroll
    for (int pass = 0; pass < 8; ++pass) {
        int p = pw + pass * 8;
        float v = tile[cw][p];
        size_t oidx = ((size_t)b * HW + p0 + p) * C + c0 + cw;
        out[oidx] = (half_t)v;
        if (outf) outf[oidx] = v;
    }
}

// ---------------- MFMA implicit-GEMM conv (unchanged R17 body) ----------------
template<int K, int UP, int REFLECT, int COB, int WM, int TW, int MINW>
__global__ __launch_bounds__(256, MINW)
void mfma_conv(const half_t* __restrict__ in1, const half_t* __restrict__ in2,
               int C1, int C2,
               const half_t* __restrict__ wt, const float* __restrict__ bias,
               void* __restrict__ outp, const float* __restrict__ zp,
               int Co, int Cop, int Hout, int Wout, int act, int outfmt,
               float* __restrict__ part, float* __restrict__ absacc)
{
    constexpr int TH = 8, PAD = K / 2;
    constexpr int PR = TH + K - 1, PW = TW + K - 1;
    constexpr int NPOS = PR * PW, KK = K * K;
    constexpr int OUT_POS = TH * TW;
    constexpr int NT  = OUT_POS / 16;
    constexpr int MT  = COB / 16;
    constexpr int WN  = 4 / WM;
    constexpr int NM  = MT / WM;
    constexpr int NNW = NT / WN;
    constexpr int LDSB = NPOS * 64;
    constexpr int NELEM = NPOS * 4;
    constexpr int NE = (NELEM + 255) / 256;
    constexpr int EPI = OUT_POS * COB * 4;
    constexpr int LDS_SZ = (2 * LDSB > EPI) ? 2 * LDSB : EPI;

    __shared__ __align__(16) char lds[LDS_SZ + 2048];

    const int Cin = C1 + C2;
    const int Hin = UP ? (Hout >> 1) : Hout;
    const int Win = UP ? (Wout >> 1) : Wout;
    const int NTX = Wout / TW, NTY = Hout / TH;

    const int tid = threadIdx.x;
    const int wv = tid >> 6, lane = tid & 63, l15 = lane & 15, kg = lane >> 4;
    const int bx = blockIdx.x;
    const int xt = (bx % NTX) * TW;
    const int yt = ((bx / NTX) % NTY) * TH;
    const int b  = bx / (NTX * NTY);
    const int ocb = blockIdx.y * COB;
    const int wm = wv % WM;
    const int wn = wv / WM;

    f32x4 acc[NM][NNW];
#pragma unroll
    for (int i = 0; i < NM; ++i)
#pragma unroll
        for (int t = 0; t < NNW; ++t) acc[i][t] = (f32x4){0.f, 0.f, 0.f, 0.f};

    int ipos[NNW];
#pragma unroll
    for (int t = 0; t < NNW; ++t) {
        int pos = (wn * NNW + t) * 16 + l15;
        ipos[t] = (pos / TW) * PW + (pos % TW);
    }

    unsigned offA[NE], offB[NE], okbits = 0;
#pragma unroll
    for (int i = 0; i < NE; ++i) {
        int e = tid + i * 256;
        if (e < NELEM) {
            int p = e >> 2;
            int g = (e & 3) ^ ((p >> 1) & 3);
            int py = p / PW, px = p % PW;
            int ly = yt + py - PAD, lx = xt + px - PAD;
            bool ok = true;
            if (REFLECT) { ly = reflect_idx(ly, Hout); lx = reflect_idx(lx, Wout); }
            else {
                ok = (ly >= 0) && (ly < Hout) && (lx >= 0) && (lx < Wout);
                if (!ok) { ly = 0; lx = 0; }
            }
            int sy = UP ? (ly >> 1) : ly;
            int sx = UP ? (lx >> 1) : lx;
            int esi = (b * Hin + sy) * Win + sx;
            offA[i] = (unsigned)(esi * C1 + g * 8);
            offB[i] = (unsigned)(esi * C2 + g * 8);
            if (ok) okbits |= (1u << i);
        }
    }

    auto issue = [&](int cb, int buf) {
        const bool inA = (cb * 32) < C1;
        const half_t* srcb = inA ? in1 + (size_t)(cb * 32)
                                 : in2 + (size_t)(cb * 32 - C1);
#pragma unroll
        for (int i = 0; i < NE; ++i) {
            const int e0 = i * 256 + wv * 64;
            if (e0 < NELEM) {
                char* lb = lds + buf * LDSB + e0 * 16;
                const int e = e0 + lane;
                if (e < NELEM) {
                    unsigned off = inA ? offA[i] : offB[i];
                    const half_t* g = ((okbits >> i) & 1) ? srcb + off
                                                          : (const half_t*)zp;
                    gl_lds16(g, lb);
                }
            }
        }
    };

    const int NCB = Cin >> 5;
    const half_t* wb[NM];
#pragma unroll
    for (int i = 0; i < NM; ++i)
        wb[i] = wt + (size_t)(ocb + (wm * NM + i) * 16 + l15) * 32 + (kg << 3);

    issue(0, 0);
    int cur = 0;
    for (int cb = 0; cb < NCB; ++cb) {
        __syncthreads();
        if (cb + 1 < NCB) issue(cb + 1, cur ^ 1);
        const size_t cbase = (size_t)cb * KK * Cop * 32;
        const char* lb = lds + cur * LDSB;

        half8 a_c[NM], b_c[NNW];
#pragma unroll
        for (int i = 0; i < NM; ++i)
            a_c[i] = *(const half8*)(wb[i] + cbase);
#pragma unroll
        for (int t = 0; t < NNW; ++t) {
            int idx = ipos[t];
            b_c[t] = *(const half8*)(lb + idx * 64 + ((kg ^ ((idx >> 1) & 3)) << 4));
        }
#pragma unroll
        for (int kk = 0; kk < KK; ++kk) {
            half8 a_n[NM], b_n[NNW];
            if (kk + 1 < KK) {
#pragma unroll
                for (int i = 0; i < NM; ++i)
                    a_n[i] = *(const half8*)(wb[i] + cbase + (size_t)(kk + 1) * Cop * 32);
                int ikk = ((kk + 1) / K) * PW + ((kk + 1) % K);
#pragma unroll
                for (int t = 0; t < NNW; ++t) {
                    int idx = ipos[t] + ikk;
                    b_n[t] = *(const half8*)(lb + idx * 64 + ((kg ^ ((idx >> 1) & 3)) << 4));
                }
            }
#pragma unroll
            for (int i = 0; i < NM; ++i)
#pragma unroll
                for (int t = 0; t < NNW; ++t)
                    acc[i][t] = __builtin_amdgcn_mfma_f32_16x16x32_f16(a_c[i], b_c[t], acc[i][t], 0, 0, 0);
            if (kk + 1 < KK) {
#pragma unroll
                for (int i = 0; i < NM; ++i) a_c[i] = a_n[i];
#pragma unroll
                for (int t = 0; t < NNW; ++t) b_c[t] = b_n[t];
            }
        }
        cur ^= 1;
    }

    // ---- epilogue ----
    if (outfmt == 1) {
        float asum = 0.f;
#pragma unroll
        for (int i = 0; i < NM; ++i)
#pragma unroll
            for (int t = 0; t < NNW; ++t) {
                int pos = (wn * NNW + t) * 16 + l15;
                int y = yt + pos / TW, x = xt + pos % TW;
#pragma unroll
                for (int j = 0; j < 4; ++j) {
                    int oc = ocb + (wm * NM + i) * 16 + kg * 4 + j;
                    if (oc < Co) {
                        float v = acc[i][t][j] + bias[oc];
                        if (act) v = tanhf(v);
                        ((float*)outp)[(((size_t)b * Co + oc) * Hout + y) * Wout + x] = v;
                        if (absacc && oc < 18) asum += fabsf(v);
                    }
                }
            }
        if (absacc) {
            float* red = (float*)(lds + LDS_SZ);
            red[tid] = asum;
            __syncthreads();
            for (int st = 128; st > 0; st >>= 1) {
                if (tid < st) red[tid] += red[tid + st];
                __syncthreads();
            }
            if (tid == 0) atomicAdd(absacc, red[0]);
        }
    } else if (outfmt == 0) {
        __syncthreads();
        half_t* tile = (half_t*)lds;
#pragma unroll
        for (int i = 0; i < NM; ++i) {
            float bv[4];
#pragma unroll
            for (int j = 0; j < 4; ++j) bv[j] = bias[ocb + (wm * NM + i) * 16 + kg * 4 + j];
#pragma unroll
            for (int t = 0; t < NNW; ++t) {
                int pos = (wn * NNW + t) * 16 + l15;
#pragma unroll
                for (int j = 0; j < 4; ++j)
                    tile[pos * COB + (wm * NM + i) * 16 + kg * 4 + j] = (half_t)(acc[i][t][j] + bv[j]);
            }
        }
        __syncthreads();
        for (int e = tid; e < OUT_POS * COB / 8; e += 256) {
            int pos = e / (COB / 8), ch = (e % (COB / 8)) * 8;
            int y = yt + pos / TW, xx = xt + pos % TW;
            short8 v = *(const short8*)(tile + pos * COB + ch);
            *(short8*)((half_t*)outp + ((size_t)(b * Hout + y) * Wout + xx) * Co + ocb + ch) = v;
        }
        if (part) {
            float* red = (float*)(lds + LDS_SZ);
            constexpr int G2 = 256 / COB;
            int c = tid % COB, r = tid / COB;
            float sm = 0.f, sq = 0.f;
            for (int p = r; p < OUT_POS; p += G2) {
                float v = (float)tile[p * COB + c];
                sm += v; sq += v * v;
            }
            red[tid * 2] = sm; red[tid * 2 + 1] = sq;
            __syncthreads();
            if (r == 0) {
                for (int g = 1; g < G2; ++g) {
                    sm += red[(g * COB + c) * 2];
                    sq += red[(g * COB + c) * 2 + 1];
                }
                int s = bx % (NTX * NTY);
                float* pp = part + ((size_t)(b * NTX * NTY + s) * Co + ocb + c) * 2;
                pp[0] = sm; pp[1] = sq;
            }
        }
    } else {
        __syncthreads();
        float* tile = (float*)lds;
#pragma unroll
        for (int i = 0; i < NM; ++i) {
            float bv[4];
#pragma unroll
            for (int j = 0; j < 4; ++j) bv[j] = bias[ocb + (wm * NM + i) * 16 + kg * 4 + j];
#pragma unroll
            for (int t = 0; t < NNW; ++t) {
                int pos = (wn * NNW + t) * 16 + l15;
#pragma unroll
                for (int j = 0; j < 4; ++j)
                    tile[pos * COB + (wm * NM + i) * 16 + kg * 4 + j] = acc[i][t][j] + bv[j];
            }
        }
        __syncthreads();
        for (int e = tid; e < OUT_POS * COB / 4; e += 256) {
            int pos = e / (COB / 4), ch = (e % (COB / 4)) * 4;
            int y = yt + pos / TW, xx = xt + pos % TW;
            f32x4 v = *(const f32x4*)(tile + pos * COB + ch);
            *(f32x4*)((float*)outp + ((size_t)(b * Hout + y) * Wout + xx) * Co + ocb + ch) = v;
        }
        if (part) {
            float* red = (float*)(lds + LDS_SZ);
            constexpr int G2 = 256 / COB;
            int c = tid % COB, r = tid / COB;
            float sm = 0.f, sq = 0.f;
            for (int p = r; p < OUT_POS; p += G2) {
                float v = tile[p * COB + c];
                sm += v; sq += v * v;
            }
            red[tid * 2] = sm; red[tid * 2 + 1] = sq;
            __syncthreads();
            if (r == 0) {
                for (int g = 1; g < G2; ++g) {
                    sm += red[(g * COB + c) * 2];
                    sq += red[(g * COB + c) * 2 + 1];
                }
                int s = bx % (NTX * NTY);
                float* pp = part + ((size_t)(b * NTX * NTY + s) * Co + ocb + c) * 2;
                pp[0] = sm; pp[1] = sq;
            }
        }
    }
}

// ---------------- MFMA deformable conv (POS-position tile, all Co per block) ----------------
template<int C, int POS, int MINW>
__global__ __launch_bounds__(256, MINW)
void mfma_dcn(const half_t* __restrict__ xs, const float* __restrict__ om,
              const half_t* __restrict__ wtd, const float* __restrict__ bias,
              half_t* __restrict__ outb, int H, int W)
{
    constexpr int NCK = C / 32;            // 32-ch chunks
    constexpr int NQ  = C / 4;             // channel quads
    constexpr int MT  = C / 16;            // m-tiles (Co == C)
    constexpr int NM  = MT / 4;            // m-tiles per wave
    constexpr int NTn = POS / 16;          // n-tiles
    constexpr int ROWS = POS / 8;          // tile rows (8 cols)
    constexpr int ITERS = POS * NQ / 256;  // gather iters per thread per tap
    constexpr int CHB = POS * 64;          // bytes per 32-ch chunk in LDS
    __shared__ __align__(16) char lds[NCK * CHB];
    __shared__ int   addrL[POS][4];
    __shared__ float wgtL[POS][4];

    const int NTX = W / 8, NTY = H / ROWS;
    const int tid = threadIdx.x;
    const int wv = tid >> 6, lane = tid & 63, l15 = lane & 15, kg = lane >> 4;
    const int bx = blockIdx.x;
    const int xt = (bx % NTX) * 8;
    const int yt = ((bx / NTX) % NTY) * ROWS;
    const int b  = bx / (NTX * NTY);
    const int HW = H * W;

    f32x4 acc[NM][NTn];
#pragma unroll
    for (int i = 0; i < NM; ++i)
#pragma unroll
        for (int t = 0; t < NTn; ++t) acc[i][t] = (f32x4){0.f, 0.f, 0.f, 0.f};

    int boff[NTn];
#pragma unroll
    for (int t = 0; t < NTn; ++t)
        boff[t] = (t * 16 + l15) * 64 + ((kg ^ (l15 & 3)) << 4);

    for (int k = 0; k < 9; ++k) {
        __syncthreads();               // prev MFMA reads of lds done
        if (tid < POS) {
            int pos = tid;
            int y = yt + (pos >> 3), x = xt + (pos & 7);
            size_t obase = (size_t)b * 27 * HW + (size_t)y * W + x;
            float offy = om[obase + (size_t)(2 * k) * HW];
            float offx = om[obase + (size_t)(2 * k + 1) * HW];
            float ml   = om[obase + (size_t)(18 + k) * HW];
            float mk = 1.f / (1.f + expf(-ml));
            float py = (float)(y - 1 + k / 3) + offy;
            float px = (float)(x - 1 + k % 3) + offx;
            float fy = floorf(py), fx = floorf(px);
            int y0 = (int)fy, x0 = (int)fx;
            float dy = py - fy, dx = px - fx;
            int y1 = y0 + 1, x1 = x0 + 1;
            bool vy0 = (y0 >= 0) && (y0 < H), vy1 = (y1 >= 0) && (y1 < H);
            bool vx0 = (x0 >= 0) && (x0 < W), vx1 = (x1 >= 0) && (x1 < W);
            wgtL[pos][0] = (vy0 && vx0) ? (1.f - dy) * (1.f - dx) * mk : 0.f;
            wgtL[pos][1] = (vy0 && vx1) ? (1.f - dy) * dx * mk : 0.f;
            wgtL[pos][2] = (vy1 && vx0) ? dy * (1.f - dx) * mk : 0.f;
            wgtL[pos][3] = (vy1 && vx1) ? dy * dx * mk : 0.f;
            int yc0 = min(max(y0, 0), H - 1), yc1 = min(max(y1, 0), H - 1);
            int xc0 = min(max(x0, 0), W - 1), xc1 = min(max(x1, 0), W - 1);
            addrL[pos][0] = ((b * H + yc0) * W + xc0) * C;
            addrL[pos][1] = ((b * H + yc0) * W + xc1) * C;
            addrL[pos][2] = ((b * H + yc1) * W + xc0) * C;
            addrL[pos][3] = ((b * H + yc1) * W + xc1) * C;
        }
        __syncthreads();               // tables ready
#pragma unroll
        for (int it = 0; it < ITERS; ++it) {
            int u = tid + it * 256;
            int pos = u / NQ;
            int cq = u % NQ;
            int c = cq * 4;
            float w00 = wgtL[pos][0], w01 = wgtL[pos][1];
            float w10 = wgtL[pos][2], w11 = wgtL[pos][3];
            const half_t* base = xs + c;
            uint2v q00 = *(const uint2v*)(base + addrL[pos][0]);
            uint2v q01 = *(const uint2v*)(base + addrL[pos][1]);
            uint2v q10 = *(const uint2v*)(base + addrL[pos][2]);
            uint2v q11 = *(const uint2v*)(base + addrL[pos][3]);
            float f0 = hlo(q00[0]) * w00 + hlo(q01[0]) * w01 + hlo(q10[0]) * w10 + hlo(q11[0]) * w11;
            float f1 = hhi(q00[0]) * w00 + hhi(q01[0]) * w01 + hhi(q10[0]) * w10 + hhi(q11[0]) * w11;
            float f2 = hlo(q00[1]) * w00 + hlo(q01[1]) * w01 + hlo(q10[1]) * w10 + hlo(q11[1]) * w11;
            float f3 = hhi(q00[1]) * w00 + hhi(q01[1]) * w01 + hhi(q10[1]) * w10 + hhi(q11[1]) * w11;
            uint2v r;
            r[0] = (unsigned)hbits(f0) | ((unsigned)hbits(f1) << 16);
            r[1] = (unsigned)hbits(f2) | ((unsigned)hbits(f3) << 16);
            int chunk = c >> 5, cpl = (c & 31) >> 1;
            *(uint2v*)(lds + chunk * CHB + pos * 64 +
                       ((((cpl >> 2) ^ (pos & 3)) << 4) | ((cpl & 3) << 2))) = r;
        }
        __syncthreads();               // gathered chunk ready
#pragma unroll
        for (int cbl = 0; cbl < NCK; ++cbl) {
            int cb = k * NCK + cbl;
            half8 a[NM];
#pragma unroll
            for (int i = 0; i < NM; ++i)
                a[i] = *(const half8*)(wtd + ((size_t)cb * C + (wv * NM + i) * 16 + l15) * 32 + (kg << 3));
            half8 bf[NTn];
#pragma unroll
            for (int t = 0; t < NTn; ++t)
                bf[t] = *(const half8*)(lds + cbl * CHB + boff[t]);
#pragma unroll
            for (int i = 0; i < NM; ++i)
#pragma unroll
                for (int t = 0; t < NTn; ++t)
                    acc[i][t] = __builtin_amdgcn_mfma_f32_16x16x32_f16(a[i], bf[t], acc[i][t], 0, 0, 0);
        }
    }

    // ---- LDS-staged coalesced epilogue (POS x C fp16 fits in chunk lds) ----
    float bv[NM][4];
#pragma unroll
    for (int i = 0; i < NM; ++i)
#pragma unroll
        for (int j = 0; j < 4; ++j) bv[i][j] = bias[(wv * NM + i) * 16 + kg * 4 + j];
    __syncthreads();
    half_t* tile = (half_t*)lds;
#pragma unroll
    for (int i = 0; i < NM; ++i)
#pragma unroll
        for (int t = 0; t < NTn; ++t) {
            int pos = t * 16 + l15;
#pragma unroll
            for (int j = 0; j < 4; ++j)
                tile[pos * C + (wv * NM + i) * 16 + kg * 4 + j] = (half_t)(acc[i][t][j] + bv[i][j]);
        }
    __syncthreads();
    for (int e = tid; e < POS * C / 8; e += 256) {
        int pos = e / (C / 8), ch = (e % (C / 8)) * 8;
        int y = yt + (pos >> 3), xx = xt + (pos & 7);
        short8 v = *(const short8*)(tile + pos * C + ch);
        *(short8*)(outb + ((size_t)(b * H + y) * W + xx) * C + ch) = v;
    }
}

// ---------------- InstanceNorm: stats reduce + normalize (p1 fused into convs) ----------------
__global__ void inorm_stats(const float* __restrict__ part, float* __restrict__ stats,
                            int Cc, int HW, int NS)
{
    int b = blockIdx.x;
    for (int c = threadIdx.x; c < Cc; c += 256) {
        float S = 0.f, Q = 0.f;
        for (int s = 0; s < NS; ++s) {
            const float* pp = part + ((size_t)(b * NS + s) * Cc + c) * 2;
            S += pp[0]; Q += pp[1];
        }
        float m = S / HW;
        float var = Q / HW - m * m;
        if (var < 0.f) var = 0.f;
        stats[(b * Cc + c) * 2]     = m;
        stats[(b * Cc + c) * 2 + 1] = rsqrtf(var + EPS);
    }
}

template<typename TI, int V>
__global__ void inorm_p2(const TI* __restrict__ in, half_t* __restrict__ out_h,
                         float* __restrict__ out_f, const float* __restrict__ resid,
                         const float* __restrict__ stats,
                         int Cc, int HW, int B, int relu)
{
    int nvec = B * HW * Cc / V;
    for (int i = blockIdx.x * 256 + threadIdx.x; i < nvec; i += gridDim.x * 256) {
        size_t E = (size_t)i * V;
        int c = (int)(E % Cc);
        int b = (int)(E / ((size_t)Cc * HW));
        float vv[V];
        if constexpr (sizeof(TI) == 2) {
            half8 hv = *(const half8*)(in + E);
#pragma unroll
            for (int j = 0; j < V; ++j) vv[j] = (float)hv[j];
        } else {
            f32x4 fv = *(const f32x4*)(in + E);
#pragma unroll
            for (int j = 0; j < V; ++j) vv[j] = fv[j];
        }
        const float* st = stats + ((size_t)b * Cc + c) * 2;
#pragma unroll
        for (int j = 0; j < V; ++j) {
            float v = (vv[j] - st[2 * j]) * st[2 * j + 1];
            if (relu) v = fmaxf(v, 0.f);
            vv[j] = v;
        }
        if (resid) {
#pragma unroll
            for (int j = 0; j < V; j += 4) {
                f32x4 rv = *(const f32x4*)(resid + E + j);
                vv[j] += rv[0]; vv[j + 1] += rv[1]; vv[j + 2] += rv[2]; vv[j + 3] += rv[3];
            }
        }
        if (out_h) {
            half8 ov = (half8)0;
#pragma unroll
            for (int j = 0; j < V; ++j) ov[j] = (half_t)vv[j];
            if constexpr (sizeof(TI) == 2) {
                *(half8*)(out_h + E) = ov;
            } else {
                for (int j = 0; j < V; ++j) out_h[E + j] = (half_t)vv[j];
            }
        }
        if (out_f) {
#pragma unroll
            for (int j = 0; j < V; j += 4) {
                f32x4 ov = { vv[j], vv[j + 1], vv[j + 2], vv[j + 3] };
                *(f32x4*)(out_f + E + j) = ov;
            }
        }
    }
}

__global__ void zero_kernel(float* p, int n) {
    int i = blockIdx.x * 256 + threadIdx.x;
    if (i < n) p[i] = 0.f;
}

__global__ void finalize_kernel(const float* __restrict__ acc, float* __restrict__ out) {
    out[0] = 0.5f * (acc[0] / (4.f * 18.f * 128.f * 128.f)
                   + acc[1] / (4.f * 18.f * 64.f * 64.f));
}

extern "C" void kernel_launch(void* const* d_in, const int* in_sizes, int n_in,
                              void* d_out, int out_size, void* d_ws, size_t ws_size,
                              hipStream_t stream)
{
    const float* x      = (const float*)d_in[0];
    const float* skip1  = (const float*)d_in[1];
    const float* skip2  = (const float*)d_in[2];
    const float* res_w  = (const float*)d_in[3];
    const float* res_b  = (const float*)d_in[4];
    const float* w1     = (const float*)d_in[5];
    const float* b1     = (const float*)d_in[6];
    const float* w2     = (const float*)d_in[7];
    const float* b2     = (const float*)d_in[8];
    const float* w3     = (const float*)d_in[9];
    const float* b3     = (const float*)d_in[10];
    const float* off2_w = (const float*)d_in[11];
    const float* off2_b = (const float*)d_in[12];
    const float* dcn2_w = (const float*)d_in[13];
    const float* dcn2_b = (const float*)d_in[14];
    const float* off1_w = (const float*)d_in[15];
    const float* off1_b = (const float*)d_in[16];
    const float* dcn1_w = (const float*)d_in[17];
    const float* dcn1_b = (const float*)d_in[18];

    char* base = (char*)d_ws;
    size_t o = 0;
    auto alloc = [&](size_t bytes) { size_t r = o; o += (bytes + 15) & ~(size_t)15; return r; };
    half_t* x_h   = (half_t*)(base + alloc(1048576ull * 2));
    float*  x_f   = (float*)(base + alloc(1048576ull * 4));
    half_t* s1c   = (half_t*)(base + alloc(4194304ull * 2));
    half_t* s2c   = (half_t*)(base + alloc(2097152ull * 2));
    float*  scrf  = (float*)(base + alloc(1048576ull * 4));
    half_t* tB_h  = (half_t*)(base + alloc(1048576ull * 2));
    float*  cur_f = (float*)(base + alloc(1048576ull * 4));
    half_t* cur_h = (half_t*)(base + alloc(1048576ull * 2));
    half_t* out1h = (half_t*)(base + alloc(2097152ull * 2));
    half_t* pre2h = (half_t*)(base + alloc(2097152ull * 2));
    half_t* out2h = (half_t*)(base + alloc(4194304ull * 2));
    half_t* pre1h = (half_t*)(base + alloc(4194304ull * 2));
    float*  om2f  = (float*)(base + alloc(442368ull * 4));
    float*  om1f  = (float*)(base + alloc(1769472ull * 4));
    half_t* wres  = (half_t*)(base + alloc(4ull * 589824 * 2));
    half_t* w1t   = (half_t*)(base + alloc(819200ull * 2));
    half_t* w2t   = (half_t*)(base + alloc(409600ull * 2));
    half_t* off2t = (half_t*)(base + alloc(73728ull * 2));
    half_t* off1t = (half_t*)(base + alloc(36864ull * 2));
    half_t* w3t   = (half_t*)(base + alloc(100352ull * 2));
    half_t* dcn2t = (half_t*)(base + alloc(147456ull * 2));
    half_t* dcn1t = (half_t*)(base + alloc(36864ull * 2));
    float*  part  = (float*)(base + alloc(262144ull * 4));
    float*  stats = (float*)(base + alloc(2048ull * 4));
    float*  zpage = (float*)(base + alloc(4096));       // zero page for OOB DMA
    float*  acc   = (float*)(base + alloc(16));
    if (ws_size < o) return;

    float* outp = (float*)d_out;

    zero_kernel<<<dim3(5), 256, 0, stream>>>(zpage, 1026);

    // ---- converts (one launch) ----
    cvt_all<<<dim3(3584), 256, 0, stream>>>(x, x_h, x_f, skip1, s1c, skip2, s2c);

    // ---- weight transforms ----
    wtrans_res4<<<dim3(9216), 256, 0, stream>>>(res_w, wres);
    wtrans_conv<<<dim3(3200), 256, 0, stream>>>(w1, w1t, 128, 128, 256, 25);
    wtrans_conv<<<dim3(1600), 256, 0, stream>>>(w2, w2t, 64, 64, 256, 25);
    wtrans_conv<<<dim3(288), 256, 0, stream>>>(off2_w, off2t, 27, 32, 256, 9);
    wtrans_conv<<<dim3(144), 256, 0, stream>>>(off1_w, off1t, 27, 32, 128, 9);
    wtrans_conv<<<dim3(392), 256, 0, stream>>>(w3, w3t, 3, 16, 128, 49);
    wtrans_dcn<<<dim3(576), 256, 0, stream>>>(dcn2_w, dcn2t, 128, 128);
    wtrans_dcn<<<dim3(144), 256, 0, stream>>>(dcn1_w, dcn1t, 64, 64);

    // ---- residual blocks (256ch @32x32): R13 config, fused p1 (NS=16 tiles) ----
    for (int i = 0; i < 2; ++i) {
        const half_t* in_h = (i == 0) ? x_h : cur_h;
        mfma_conv<3, 0, 1, 32, 2, 8, 4><<<dim3(64, 8), 256, 0, stream>>>(
            in_h, nullptr, 256, 0, wres + (size_t)(i * 2) * 589824, res_b + (i * 2) * 256,
            scrf, zpage, 256, 256, 32, 32, 0, 2, part, nullptr);
        inorm_stats<<<dim3(4), 256, 0, stream>>>(part, stats, 256, 1024, 16);
        inorm_p2<float, 4><<<dim3(1024), 256, 0, stream>>>(scrf, tB_h, nullptr, nullptr,
                                                           stats, 256, 1024, 4, 1);
        mfma_conv<3, 0, 1, 32, 2, 8, 4><<<dim3(64, 8), 256, 0, stream>>>(
            tB_h, nullptr, 256, 0, wres + (size_t)(i * 2 + 1) * 589824, res_b + (i * 2 + 1) * 256,
            scrf, zpage, 256, 256, 32, 32, 0, 2, part, nullptr);
        inorm_stats<<<dim3(4), 256, 0, stream>>>(part, stats, 256, 1024, 16);
        inorm_p2<float, 4><<<dim3(1024), 256, 0, stream>>>(scrf, cur_h, cur_f,
                                                           (i == 0) ? x_f : cur_f,
                                                           stats, 256, 1024, 4, 0);
    }

    // ---- conv1: up2+refpad2+5x5 (256->128) @64x64, fused p1 (NS=32 tiles) ----
    mfma_conv<5, 1, 1, 32, 2, 16, 2><<<dim3(128, 4), 256, 0, stream>>>(
        cur_h, nullptr, 256, 0, w1t, b1, out1h, zpage, 128, 128, 64, 64, 0, 0, part, nullptr);
    inorm_stats<<<dim3(4), 256, 0, stream>>>(part, stats, 128, 4096, 32);
    inorm_p2<half_t, 8><<<dim3(1024), 256, 0, stream>>>(out1h, out1h, nullptr, nullptr,
                                                        stats, 128, 4096, 4, 1);

    // ---- om2 = 3x3 zero-pad conv -> 27ch fp32 NCHW, fused |offset| (acc+1) ----
    mfma_conv<3, 0, 0, 32, 2, 8, 4><<<dim3(256, 1), 256, 0, stream>>>(
        out1h, s2c, 128, 128, off2t, off2_b, om2f, zpage, 27, 32, 64, 64, 0, 1,
        nullptr, acc + 1);

    // ---- pre2 = deform_conv(skip2, om2): 32-pos tiles -> 512 blocks (2/CU) ----
    mfma_dcn<128, 32, 2><<<dim3(512), 256, 0, stream>>>(s2c, om2f, dcn2t, dcn2_b, pre2h, 64, 64);

    // ---- conv2: R13 config, fused p1 (NS=128 tiles) ----
    mfma_conv<5, 1, 1, 64, 2, 16, 2><<<dim3(512, 1), 256, 0, stream>>>(
        pre2h, out1h, 128, 128, w2t, b2, out2h, zpage, 64, 64, 128, 128, 0, 0, part, nullptr);
    inorm_stats<<<dim3(4), 256, 0, stream>>>(part, stats, 64, 16384, 128);
    inorm_p2<half_t, 8><<<dim3(2048), 256, 0, stream>>>(out2h, out2h, nullptr, nullptr,
                                                        stats, 64, 16384, 4, 1);

    // ---- om1 = 3x3 zero-pad conv -> 27ch fp32 NCHW, fused |offset| (acc+0) ----
    mfma_conv<3, 0, 0, 32, 2, 8, 4><<<dim3(1024, 1), 256, 0, stream>>>(
        out2h, s1c, 64, 64, off1t, off1_b, om1f, zpage, 27, 32, 128, 128, 0, 1,
        nullptr, acc + 0);

    // ---- pre1 = deform_conv(skip1, om1): 64-pos tiles, 1024 blocks (4/CU) ----
    mfma_dcn<64, 64, 2><<<dim3(1024), 256, 0, stream>>>(s1c, om1f, dcn1t, dcn1_b, pre1h, 128, 128);

    // ---- final: 7x7 refpad3 concat[pre1,out2] -> 3ch fp32 NCHW + tanh ----
    mfma_conv<7, 0, 1, 16, 1, 8, 4><<<dim3(1024, 1), 256, 0, stream>>>(
        pre1h, out2h, 64, 64, w3t, b3, outp, zpage, 3, 16, 128, 128, 1, 1,
        nullptr, nullptr);

    // ---- offset_sum scalar ----
    finalize_kernel<<<dim3(1), dim3(1), 0, stream>>>(acc, outp + 196608);
}